// Round 13
// baseline (1580.075 us; speedup 1.0000x reference)
//
#include <hip/hip_runtime.h>

typedef unsigned short dg35_u16;
typedef unsigned int   dg35_u32;

constexpr int dgN  = 50000;
constexpr int dgE  = 400000;
constexpr int dgG  = 1024;
constexpr int dgC  = 128;
constexpr int dgC2 = 256;

typedef __attribute__((ext_vector_type(8))) short dg35_s8v;   // 8 bf16 (4 VGPR)
typedef __attribute__((ext_vector_type(4))) float dg35_f4v;   // MFMA acc

__device__ __forceinline__ float dg35_bf2f(dg35_u16 u){
  return __uint_as_float(((dg35_u32)u) << 16);
}
__device__ __forceinline__ dg35_u16 dg35_f2bf(float f){
  dg35_u32 u = __float_as_uint(f);
  u += 0x7FFFu + ((u >> 16) & 1u);
  return (dg35_u16)(u >> 16);
}
__device__ __forceinline__ float dg35_ldx(const void* p, size_t i, int af){
  return af ? ((const float*)p)[i] : dg35_bf2f(((const dg35_u16*)p)[i]);
}
__device__ __forceinline__ void dg35_stx(void* p, size_t i, int af, float v){
  if (af) ((float*)p)[i] = v; else ((dg35_u16*)p)[i] = dg35_f2bf(v);
}

// Symbol from the harness template; kept but never launched.
__global__ void DeeperGCN_35820027248884_kernel(){}

// ---------------- CSR build ----------------
__global__ void dg35_count(const int* __restrict__ dst, int* __restrict__ deg, int e){
  int j = blockIdx.x*256 + threadIdx.x;
  if (j < e) atomicAdd(&deg[dst[j]], 1);
}

__global__ void dg35_s1(const int* __restrict__ deg, int* __restrict__ bsum, int n){
  __shared__ int sm[256];
  int t = threadIdx.x, b = blockIdx.x;
  int idx = b*256 + t;
  sm[t] = (idx < n) ? deg[idx] : 0;
  __syncthreads();
  for (int s = 128; s > 0; s >>= 1){
    if (t < s) sm[t] += sm[t+s];
    __syncthreads();
  }
  if (t == 0) bsum[b] = sm[0];
}

__global__ void dg35_s2(const int* __restrict__ bsum, int* __restrict__ boff, int nb){
  __shared__ int sm[256];
  int t = threadIdx.x;
  int v = (t < nb) ? bsum[t] : 0;
  sm[t] = v;
  __syncthreads();
  for (int s = 1; s < 256; s <<= 1){
    int u = (t >= s) ? sm[t-s] : 0;
    __syncthreads();
    sm[t] += u;
    __syncthreads();
  }
  if (t < nb) boff[t] = sm[t] - v;
}

__global__ void dg35_s3(const int* __restrict__ deg, const int* __restrict__ boff,
                        int* __restrict__ off, int* __restrict__ cur, int n){
  __shared__ int sm[256];
  int t = threadIdx.x, b = blockIdx.x;
  int idx = b*256 + t;
  int v = (idx < n) ? deg[idx] : 0;
  sm[t] = v;
  __syncthreads();
  for (int s = 1; s < 256; s <<= 1){
    int u = (t >= s) ? sm[t-s] : 0;
    __syncthreads();
    sm[t] += u;
    __syncthreads();
  }
  if (idx < n){
    int e = boff[b] + sm[t] - v;
    off[idx] = e; cur[idx] = e;
  }
  if (idx == 0) off[n] = dgE;
}

__global__ void dg35_scatter(const int* __restrict__ ei, const int* __restrict__ ea,
                             int* __restrict__ cur, dg35_u32* __restrict__ packed, int e){
  int j = blockIdx.x*256 + threadIdx.x;
  if (j >= e) return;
  int s = ei[j], d = ei[e + j];
  dg35_u32 a0 = (dg35_u32)ea[3*j], a1 = (dg35_u32)ea[3*j+1], a2 = (dg35_u32)ea[3*j+2];
  int pos = atomicAdd(&cur[d], 1);
  packed[pos] = (dg35_u32)s | (a0<<17) | (a1<<20) | (a2<<23);
}

__global__ void dg35_gstart(const int* __restrict__ batch, int* __restrict__ gs, int n, int g){
  int i = blockIdx.x*256 + threadIdx.x;
  if (i > g) return;
  if (i == g){ gs[i] = n; return; }
  int lo = 0, hi = n;
  while (lo < hi){ int mid = (lo+hi)>>1; if (batch[mid] < i) lo = mid+1; else hi = mid; }
  gs[i] = lo;
}

// ---------------- encoders / weight prep ----------------
__global__ __launch_bounds__(128)
void dg35_atom(const int* __restrict__ x, const float* __restrict__ aemb,
               const float* __restrict__ vne, void* __restrict__ h, int af){
  int i = blockIdx.x, c = threadIdx.x;
  float acc = vne[c];
  #pragma unroll
  for (int f = 0; f < 9; ++f){
    int idx = x[i*9 + f];
    acc += aemb[(f*128 + idx)*dgC + c];
  }
  dg35_stx(h, (size_t)i*dgC + c, af, acc);
}

__global__ void dg35_vninit(const float* __restrict__ vne, float* __restrict__ vn){
  int i = blockIdx.x*256 + threadIdx.x;
  if (i < dgG*dgC) vn[i] = vne[i & (dgC-1)];
}

// combo table: ecomb[c9][c] = bemb[a0][c] + bemb[8+a1][c] + bemb[16+a2][c]
__global__ __launch_bounds__(128)
void dg35_ecomb(const float* __restrict__ bemb, float* __restrict__ ecomb){
  int c9 = blockIdx.x, t = threadIdx.x;
  int a0 = c9 & 7, a1 = (c9 >> 3) & 7, a2 = (c9 >> 6) & 7;
  ecomb[c9*dgC + t] = bemb[a0*dgC + t] + bemb[(8+a1)*dgC + t] + bemb[(16+a2)*dgC + t];
}

// transpose+convert conv weights to SPLIT bf16 (hi+lo) in [l][n][k] layout
__global__ void dg35_wconv(const float* __restrict__ W1, const float* __restrict__ W2,
                           short* __restrict__ Wt1h, short* __restrict__ Wt1l,
                           short* __restrict__ Wt2h, short* __restrict__ Wt2l){
  int i = blockIdx.x*256 + threadIdx.x;
  constexpr int per = 7*256*128;
  float w;
  short* ph; short* pl; int oidx;
  if (i < per){
    int l = i >> 15;
    int rem = i & 32767;
    int n = rem >> 7;
    int k = rem & 127;
    w = W1[l*32768 + k*256 + n];
    ph = Wt1h; pl = Wt1l; oidx = i;
  } else {
    int j = i - per;
    int l = j >> 15;
    int rem = j & 32767;
    int n = rem >> 8;
    int k = rem & 255;
    w = W2[l*32768 + k*128 + n];
    ph = Wt2h; pl = Wt2l; oidx = j;
  }
  dg35_u16 hi = dg35_f2bf(w);
  float lo = w - dg35_bf2f(hi);
  ph[oidx] = (short)hi;
  pl[oidx] = (short)dg35_f2bf(lo);
}

__global__ void dg35_zero(float* a, float* b, float* c_, float* d){
  int t = threadIdx.x;
  if (t < 512) a[t] = 0.f;
  if (t < 256){ b[t]=0.f; c_[t]=0.f; d[t]=0.f; }
}

// ------------- GENConv softmax aggr: exp-direct (shift-8), 2 ch/lane, 2 edge streams ----
// msg = relu(h+e)+1e-7 is BN-bounded (<< 80), so exp(msg-8) cannot overflow; the
// constant shift cancels exactly in w/s. No running max -> 4 VALU ops per update.
__global__ __launch_bounds__(256)
void dg35_gb2(const float* __restrict__ hin, const dg35_u32* __restrict__ packed,
              const int* __restrict__ off, const float* __restrict__ ecomb,
              float* __restrict__ hh){
  int i = blockIdx.x*4 + (threadIdx.x >> 6);
  if (i >= dgN) return;
  int c = (threadIdx.x & 63) * 2;
  int b0 = off[i], b1 = off[i+1];
  float2 self = *reinterpret_cast<const float2*>(hin + (size_t)i*dgC + c);
  float sA0=0.f, wA0=0.f, sA1=0.f, wA1=0.f;
  float sB0=0.f, wB0=0.f, sB1=0.f, wB1=0.f;
  int p = b0;
  for (; p + 1 < b1; p += 2){
    dg35_u32 pkA = packed[p], pkB = packed[p+1];
    int srcA = (int)(pkA & 0x1FFFFu), srcB = (int)(pkB & 0x1FFFFu);
    float2 hA = *reinterpret_cast<const float2*>(hin + (size_t)srcA*dgC + c);
    float2 hB = *reinterpret_cast<const float2*>(hin + (size_t)srcB*dgC + c);
    float2 eA = *reinterpret_cast<const float2*>(ecomb + (size_t)(pkA>>17)*dgC + c);
    float2 eB = *reinterpret_cast<const float2*>(ecomb + (size_t)(pkB>>17)*dgC + c);
    float msgA0 = fmaxf(hA.x + eA.x, 0.f) + 1e-7f;
    float msgA1 = fmaxf(hA.y + eA.y, 0.f) + 1e-7f;
    float msgB0 = fmaxf(hB.x + eB.x, 0.f) + 1e-7f;
    float msgB1 = fmaxf(hB.y + eB.y, 0.f) + 1e-7f;
    float tA0 = __expf(msgA0 - 8.f), tA1 = __expf(msgA1 - 8.f);
    float tB0 = __expf(msgB0 - 8.f), tB1 = __expf(msgB1 - 8.f);
    sA0 += tA0; wA0 = fmaf(msgA0, tA0, wA0);
    sA1 += tA1; wA1 = fmaf(msgA1, tA1, wA1);
    sB0 += tB0; wB0 = fmaf(msgB0, tB0, wB0);
    sB1 += tB1; wB1 = fmaf(msgB1, tB1, wB1);
  }
  if (p < b1){
    dg35_u32 pkA = packed[p];
    int srcA = (int)(pkA & 0x1FFFFu);
    float2 hA = *reinterpret_cast<const float2*>(hin + (size_t)srcA*dgC + c);
    float2 eA = *reinterpret_cast<const float2*>(ecomb + (size_t)(pkA>>17)*dgC + c);
    float msg0 = fmaxf(hA.x + eA.x, 0.f) + 1e-7f;
    float msg1 = fmaxf(hA.y + eA.y, 0.f) + 1e-7f;
    float t0 = __expf(msg0 - 8.f), t1 = __expf(msg1 - 8.f);
    sA0 += t0; wA0 = fmaf(msg0, t0, wA0);
    sA1 += t1; wA1 = fmaf(msg1, t1, wA1);
  }
  float s0 = sA0 + sB0, w0 = wA0 + wB0;
  float s1 = sA1 + sB1, w1 = wA1 + wB1;
  float2 o;
  o.x = self.x + ((b1 > b0) ? (w0 / (s0 + 1e-16f)) : 0.f);
  o.y = self.y + ((b1 > b0) ? (w1 / (s1 + 1e-16f)) : 0.f);
  *reinterpret_cast<float2*>(hh + (size_t)i*dgC + c) = o;
}

// ---- split-bf16 MFMA GEMM, BM=128, A+B LDS-staged (swizzled), prefetch,
//      fused column stats with 8-way replicated accumulators, XCD chunk swizzle ----
// grid = dim3(NC/64, ceil(M/128)); 4 waves x (32 rows x 64 cols).
__global__ __launch_bounds__(256)
void dg35_gemmx(const float* __restrict__ A, const short* __restrict__ Whi,
                const short* __restrict__ Wlo, const float* __restrict__ bias,
                const float* __restrict__ ab, const float* __restrict__ res,
                float* __restrict__ Cout, float* __restrict__ st,
                int M, int K, int NC, int trans, int addres){
  __shared__ short Ahi[128*64];  // 16 KB
  __shared__ short Alo[128*64];  // 16 KB
  __shared__ short Bhs[64*64];   // 8 KB
  __shared__ short Bls[64*64];   // 8 KB
  int tid = threadIdx.x;
  // bijective XCD chunk swizzle (m204)
  int nwg = gridDim.x * gridDim.y;
  int lin = blockIdx.y * gridDim.x + blockIdx.x;
  int q8 = nwg >> 3, r8 = nwg & 7;
  int xcd = lin & 7, pos = lin >> 3;
  int wg = (xcd < r8) ? (xcd*(q8+1) + pos) : (r8*(q8+1) + (xcd-r8)*q8 + pos);
  int bn = (wg % gridDim.x) * 64;
  int bm = (wg / gridDim.x) * 128;
  float* stc = st + (size_t)(wg & 7) * 2 * NC;
  int lane = tid & 63;
  int wv = tid >> 6;
  int l15 = lane & 15;
  int l4  = lane >> 4;
  dg35_f4v acc[2][4] = {};

  int r = tid >> 1;            // A staging row 0..127
  int ch = tid & 1;            // col half (32 f32)
  int grow = bm + r;
  // B staging coords
  int nB = tid >> 2;
  int kqB = (tid & 3) * 16;
  const short* wbase_h = Whi + (size_t)(bn + nB)*K + kqB;
  const short* wbase_l = Wlo + (size_t)(bn + nB)*K + kqB;

  float4 va[8];
  {
    const float* ap = A + (size_t)grow*K + ch*32;
    if (grow < M){
      #pragma unroll
      for (int q2 = 0; q2 < 8; ++q2) va[q2] = *reinterpret_cast<const float4*>(ap + q2*4);
    } else {
      #pragma unroll
      for (int q2 = 0; q2 < 8; ++q2) va[q2] = make_float4(0.f,0.f,0.f,0.f);
    }
  }

  for (int k0 = 0; k0 < K; k0 += 64){
    // issue B loads (latency overlaps A conversion)
    uint4 bth[2], btl[2];
    #pragma unroll
    for (int j = 0; j < 2; ++j){
      bth[j] = *reinterpret_cast<const uint4*>(wbase_h + k0 + j*8);
      btl[j] = *reinterpret_cast<const uint4*>(wbase_l + k0 + j*8);
    }
    // convert current A tile -> swizzled split-bf16 LDS
    {
      float xv[32];
      #pragma unroll
      for (int q2 = 0; q2 < 8; ++q2){
        xv[q2*4+0]=va[q2].x; xv[q2*4+1]=va[q2].y;
        xv[q2*4+2]=va[q2].z; xv[q2*4+3]=va[q2].w;
      }
      if (trans){
        #pragma unroll
        for (int q2 = 0; q2 < 32; ++q2){
          int kk = k0 + ch*32 + q2;
          xv[q2] = fmaxf(xv[q2]*ab[kk] + ab[K + kk], 0.f);
        }
      }
      #pragma unroll
      for (int g = 0; g < 4; ++g){
        uint4 wh, wl;
        unsigned* hp = (unsigned*)&wh;
        unsigned* lp = (unsigned*)&wl;
        #pragma unroll
        for (int d = 0; d < 4; ++d){
          float f0 = xv[g*8 + d*2], f1 = xv[g*8 + d*2 + 1];
          dg35_u16 h0 = dg35_f2bf(f0), h1 = dg35_f2bf(f1);
          dg35_u16 l0 = dg35_f2bf(f0 - dg35_bf2f(h0));
          dg35_u16 l1 = dg35_f2bf(f1 - dg35_bf2f(h1));
          hp[d] = (dg35_u32)h0 | ((dg35_u32)h1 << 16);
          lp[d] = (dg35_u32)l0 | ((dg35_u32)l1 << 16);
        }
        int slot = (ch*4 + g) ^ (r & 7);
        *reinterpret_cast<uint4*>(&Ahi[r*64 + slot*8]) = wh;
        *reinterpret_cast<uint4*>(&Alo[r*64 + slot*8]) = wl;
      }
    }
    // write B to swizzled LDS
    #pragma unroll
    for (int j = 0; j < 2; ++j){
      int slot = ((kqB >> 3) + j) ^ (nB & 7);
      *reinterpret_cast<uint4*>(&Bhs[nB*64 + slot*8]) = bth[j];
      *reinterpret_cast<uint4*>(&Bls[nB*64 + slot*8]) = btl[j];
    }
    __syncthreads();
    // prefetch next A tile (overlaps MFMA below)
    if (k0 + 64 < K && grow < M){
      const float* ap = A + (size_t)grow*K + k0 + 64 + ch*32;
      #pragma unroll
      for (int q2 = 0; q2 < 8; ++q2) va[q2] = *reinterpret_cast<const float4*>(ap + q2*4);
    }
    // MFMA: 2 K-steps x 2 row-frags x 4 col-frags x 3 (split terms)
    #pragma unroll
    for (int ks = 0; ks < 2; ++ks){
      dg35_s8v bh[4], bl[4];
      #pragma unroll
      for (int nf = 0; nf < 4; ++nf){
        int n = nf*16 + l15;
        int slot = (ks*4 + l4) ^ (n & 7);
        bh[nf] = *reinterpret_cast<const dg35_s8v*>(&Bhs[n*64 + slot*8]);
        bl[nf] = *reinterpret_cast<const dg35_s8v*>(&Bls[n*64 + slot*8]);
      }
      #pragma unroll
      for (int mf = 0; mf < 2; ++mf){
        int row = wv*32 + mf*16 + l15;
        int slotA = (ks*4 + l4) ^ (row & 7);
        dg35_s8v ah = *reinterpret_cast<const dg35_s8v*>(&Ahi[row*64 + slotA*8]);
        dg35_s8v al = *reinterpret_cast<const dg35_s8v*>(&Alo[row*64 + slotA*8]);
        #pragma unroll
        for (int nf = 0; nf < 4; ++nf){
          acc[mf][nf] = __builtin_amdgcn_mfma_f32_16x16x32_bf16(ah, bh[nf], acc[mf][nf], 0, 0, 0);
          acc[mf][nf] = __builtin_amdgcn_mfma_f32_16x16x32_bf16(al, bh[nf], acc[mf][nf], 0, 0, 0);
          acc[mf][nf] = __builtin_amdgcn_mfma_f32_16x16x32_bf16(ah, bl[nf], acc[mf][nf], 0, 0, 0);
        }
      }
    }
    __syncthreads();
  }
  // epilogue: write + per-lane col partial stats
  float s[4] = {0.f,0.f,0.f,0.f}, q[4] = {0.f,0.f,0.f,0.f};
  #pragma unroll
  for (int mf = 0; mf < 2; ++mf){
    #pragma unroll
    for (int e = 0; e < 4; ++e){
      int rr = bm + wv*32 + mf*16 + l4*4 + e;
      if (rr >= M) continue;
      #pragma unroll
      for (int nf = 0; nf < 4; ++nf){
        int cc = bn + nf*16 + l15;
        float v = acc[mf][nf][e] + bias[cc];
        size_t idx = (size_t)rr*NC + cc;
        if (addres) v += res[idx];
        Cout[idx] = v;
        s[nf] += v; q[nf] += v*v;
      }
    }
  }
  #pragma unroll
  for (int nf = 0; nf < 4; ++nf){
    s[nf] += __shfl_xor(s[nf], 16); s[nf] += __shfl_xor(s[nf], 32);
    q[nf] += __shfl_xor(q[nf], 16); q[nf] += __shfl_xor(q[nf], 32);
  }
  __syncthreads();
  float* red = (float*)Ahi;
  if (l4 == 0){
    #pragma unroll
    for (int nf = 0; nf < 4; ++nf){
      red[wv*128 + nf*16 + l15] = s[nf];
      red[wv*128 + 64 + nf*16 + l15] = q[nf];
    }
  }
  __syncthreads();
  if (tid < 64){
    float S = red[tid] + red[128+tid] + red[256+tid] + red[384+tid];
    float Q = red[64+tid] + red[192+tid] + red[320+tid] + red[448+tid];
    atomicAdd(&stc[bn + tid], S);
    atomicAdd(&stc[NC + bn + tid], Q);
  }
}

// -------- VALU GEMM (dual-precision) — tier-B fallback only --------
__global__ __launch_bounds__(256)
void dg35_gemm_h(const void* __restrict__ A, const float* __restrict__ W,
                 const float* __restrict__ bias, const float* __restrict__ ab,
                 const void* __restrict__ res, void* __restrict__ Cout,
                 int M, int K, int NC, int trans, int addres, int af){
  __shared__ float At[32][65];
  __shared__ float Bt[32][64];
  int bm = blockIdx.x * 64;
  int bn = blockIdx.y * 64;
  int tid = threadIdx.x;
  int tx = tid & 15, ty = tid >> 4;
  float acc[4][4];
  #pragma unroll
  for (int i2 = 0; i2 < 4; ++i2)
    #pragma unroll
    for (int j2 = 0; j2 < 4; ++j2) acc[i2][j2] = 0.f;

  for (int k0 = 0; k0 < K; k0 += 32){
    int r = tid >> 3;
    int kq = (tid & 7) * 4;
    #pragma unroll
    for (int half = 0; half < 2; ++half){
      int rr = r + half*32;
      int grow = bm + rr;
      float vv[4] = {0.f, 0.f, 0.f, 0.f};
      if (grow < M){
        if (af){
          float4 v4 = *reinterpret_cast<const float4*>((const float*)A + (size_t)grow*K + k0 + kq);
          vv[0] = v4.x; vv[1] = v4.y; vv[2] = v4.z; vv[3] = v4.w;
        } else {
          ushort4 v4 = *reinterpret_cast<const ushort4*>((const dg35_u16*)A + (size_t)grow*K + k0 + kq);
          vv[0] = dg35_bf2f(v4.x); vv[1] = dg35_bf2f(v4.y);
          vv[2] = dg35_bf2f(v4.z); vv[3] = dg35_bf2f(v4.w);
        }
      }
      #pragma unroll
      for (int i2 = 0; i2 < 4; ++i2){
        float xv = vv[i2];
        if (trans){
          int kk = k0 + kq + i2;
          xv = fmaxf(xv*ab[kk] + ab[K + kk], 0.f);
        }
        At[kq + i2][rr] = xv;
      }
    }
    {
      int kr = tid >> 3;
      int cq = (tid & 7) * 8;
      const float* wp = W + (size_t)(k0 + kr)*NC + bn + cq;
      #pragma unroll
      for (int i2 = 0; i2 < 8; ++i2) Bt[kr][cq + i2] = wp[i2];
    }
    __syncthreads();
    #pragma unroll
    for (int kk = 0; kk < 32; ++kk){
      float a4[4], b4[4];
      #pragma unroll
      for (int i2 = 0; i2 < 4; ++i2) a4[i2] = At[kk][ty*4 + i2];
      #pragma unroll
      for (int j2 = 0; j2 < 4; ++j2) b4[j2] = Bt[kk][tx*4 + j2];
      #pragma unroll
      for (int i2 = 0; i2 < 4; ++i2)
        #pragma unroll
        for (int j2 = 0; j2 < 4; ++j2)
          acc[i2][j2] += a4[i2]*b4[j2];
    }
    __syncthreads();
  }
  #pragma unroll
  for (int i2 = 0; i2 < 4; ++i2){
    int rr = bm + ty*4 + i2;
    if (rr >= M) continue;
    #pragma unroll
    for (int j2 = 0; j2 < 4; ++j2){
      int cc = bn + tx*4 + j2;
      float v = acc[i2][j2] + bias[cc];
      size_t idx = (size_t)rr*NC + cc;
      if (addres) v += dg35_ldx(res, idx, af);
      dg35_stx(Cout, idx, af, v);
    }
  }
}

// -------- GEMM, A f32, W f32, f32 out (virtual-node MLP, M=1024) --------
__global__ __launch_bounds__(256)
void dg35_gemm_v(const float* __restrict__ A, const float* __restrict__ W,
                 const float* __restrict__ bias, const float* __restrict__ ab,
                 float* __restrict__ Cout, int M, int K, int NC, int trans){
  __shared__ float At[32][65];
  __shared__ float Bt[32][64];
  int bm = blockIdx.x * 64;
  int bn = blockIdx.y * 64;
  int tid = threadIdx.x;
  int tx = tid & 15, ty = tid >> 4;
  float acc[4][4];
  #pragma unroll
  for (int i2 = 0; i2 < 4; ++i2)
    #pragma unroll
    for (int j2 = 0; j2 < 4; ++j2) acc[i2][j2] = 0.f;

  for (int k0 = 0; k0 < K; k0 += 32){
    int r = tid >> 3;
    int kq = (tid & 7) * 4;
    #pragma unroll
    for (int half = 0; half < 2; ++half){
      int rr = r + half*32;
      int grow = bm + rr;
      float vv[4] = {0.f, 0.f, 0.f, 0.f};
      if (grow < M){
        float4 v4 = *reinterpret_cast<const float4*>(A + (size_t)grow*K + k0 + kq);
        vv[0] = v4.x; vv[1] = v4.y; vv[2] = v4.z; vv[3] = v4.w;
      }
      #pragma unroll
      for (int i2 = 0; i2 < 4; ++i2){
        float xv = vv[i2];
        if (trans){
          int kk = k0 + kq + i2;
          xv = fmaxf(xv*ab[kk] + ab[K + kk], 0.f);
        }
        At[kq + i2][rr] = xv;
      }
    }
    {
      int kr = tid >> 3;
      int cq = (tid & 7) * 8;
      const float* wp = W + (size_t)(k0 + kr)*NC + bn + cq;
      #pragma unroll
      for (int i2 = 0; i2 < 8; ++i2) Bt[kr][cq + i2] = wp[i2];
    }
    __syncthreads();
    #pragma unroll
    for (int kk = 0; kk < 32; ++kk){
      float a4[4], b4[4];
      #pragma unroll
      for (int i2 = 0; i2 < 4; ++i2) a4[i2] = At[kk][ty*4 + i2];
      #pragma unroll
      for (int j2 = 0; j2 < 4; ++j2) b4[j2] = Bt[kk][tx*4 + j2];
      #pragma unroll
      for (int i2 = 0; i2 < 4; ++i2)
        #pragma unroll
        for (int j2 = 0; j2 < 4; ++j2)
          acc[i2][j2] += a4[i2]*b4[j2];
    }
    __syncthreads();
  }
  #pragma unroll
  for (int i2 = 0; i2 < 4; ++i2){
    int rr = bm + ty*4 + i2;
    if (rr >= M) continue;
    #pragma unroll
    for (int j2 = 0; j2 < 4; ++j2){
      int cc = bn + tx*4 + j2;
      Cout[(size_t)rr*NC + cc] = acc[i2][j2] + bias[cc];
    }
  }
}

// ---------------- BN statistics (small f32 buffers: zv1/zv2) ----------------
__global__ __launch_bounds__(256)
void dg35_cs4(const float* __restrict__ Z, float* __restrict__ st, int n, int ncols){
  int t = threadIdx.x;
  int lpr = ncols >> 2;
  int rl = t / lpr;
  int rpb = 256 / lpr;
  int cq = (t - rl*lpr) * 4;
  float4 s = make_float4(0.f,0.f,0.f,0.f);
  float4 q = make_float4(0.f,0.f,0.f,0.f);
  for (int rr = blockIdx.x*rpb + rl; rr < n; rr += gridDim.x*rpb){
    float4 v = *reinterpret_cast<const float4*>(Z + (size_t)rr*ncols + cq);
    s.x += v.x; s.y += v.y; s.z += v.z; s.w += v.w;
    q.x += v.x*v.x; q.y += v.y*v.y; q.z += v.z*v.z; q.w += v.w*v.w;
  }
  __shared__ float sm[256*8];
  float* my = &sm[t*8];
  my[0]=s.x; my[1]=s.y; my[2]=s.z; my[3]=s.w;
  my[4]=q.x; my[5]=q.y; my[6]=q.z; my[7]=q.w;
  __syncthreads();
  if (rl == 0){
    float a[8];
    #pragma unroll
    for (int d = 0; d < 8; ++d) a[d] = my[d];
    for (int j = 1; j < rpb; ++j){
      const float* o2 = &sm[(t + j*lpr)*8];
      #pragma unroll
      for (int d = 0; d < 8; ++d) a[d] += o2[d];
    }
    #pragma unroll
    for (int d = 0; d < 4; ++d) atomicAdd(&st[cq + d], a[d]);
    #pragma unroll
    for (int d = 0; d < 4; ++d) atomicAdd(&st[ncols + cq + d], a[4 + d]);
  }
}

// tier-B fallback colstats
__global__ void dg35_colstats(const void* __restrict__ Z, float* __restrict__ st,
                              int n, int ncols, int af){
  int tid = threadIdx.x;
  int c = tid & (ncols - 1);
  int rl = tid / ncols;
  int rpb = 256 / ncols;
  float s = 0.f, q = 0.f;
  for (int rr = blockIdx.x*rpb + rl; rr < n; rr += gridDim.x*rpb){
    float v = dg35_ldx(Z, (size_t)rr*ncols + c, af);
    s += v; q += v*v;
  }
  atomicAdd(&st[c], s);
  atomicAdd(&st[ncols + c], q);
}

// finalize BN affine from (possibly replicated) stats
__global__ void dg35_fin(const float* __restrict__ st, const float* __restrict__ g,
                         const float* __restrict__ b, float* __restrict__ ab,
                         float inv_n, int ncols, int ncopy){
  int c = threadIdx.x + blockIdx.x*256;
  if (c >= ncols) return;
  float m = 0.f, q = 0.f;
  for (int k = 0; k < ncopy; ++k){
    m += st[(size_t)k*2*ncols + c];
    q += st[(size_t)k*2*ncols + ncols + c];
  }
  m *= inv_n;
  float var = q*inv_n - m*m;
  float rstd = rsqrtf(var + 1e-5f);
  float a = g[c]*rstd;
  ab[c] = a;
  ab[ncols + c] = b[c] - m*a;
}

// ---------------- elementwise / segment ops ----------------
__global__ void dg35_h24(const float* __restrict__ h, const float* __restrict__ ab,
                         float* __restrict__ h2){
  int i = blockIdx.x*256 + threadIdx.x;
  int c = (i & 31) * 4;
  float4 v = reinterpret_cast<const float4*>(h)[i];
  v.x = fmaxf(v.x*ab[c+0] + ab[dgC+c+0], 0.f);
  v.y = fmaxf(v.y*ab[c+1] + ab[dgC+c+1], 0.f);
  v.z = fmaxf(v.z*ab[c+2] + ab[dgC+c+2], 0.f);
  v.w = fmaxf(v.w*ab[c+3] + ab[dgC+c+3], 0.f);
  reinterpret_cast<float4*>(h2)[i] = v;
}

__global__ void dg35_h2(const void* __restrict__ h, const float* __restrict__ ab,
                        void* __restrict__ h2, int af){
  int i = blockIdx.x*256 + threadIdx.x;
  int c = i & (dgC-1);
  dg35_stx(h2, i, af, fmaxf(dg35_ldx(h, i, af)*ab[c] + ab[dgC + c], 0.f));
}

__global__ __launch_bounds__(128)
void dg35_vt4(const float* __restrict__ h2, const float* __restrict__ vn,
              const int* __restrict__ gs, float* __restrict__ vt){
  int g = blockIdx.x, t = threadIdx.x;
  int rl = t >> 5, cl = t & 31;
  int cq = cl*4;
  int r0 = gs[g], r1 = gs[g+1];
  float4 s = make_float4(0.f,0.f,0.f,0.f);
  for (int rr = r0 + rl; rr < r1; rr += 4){
    float4 v = *reinterpret_cast<const float4*>(h2 + (size_t)rr*dgC + cq);
    s.x += v.x; s.y += v.y; s.z += v.z; s.w += v.w;
  }
  __shared__ float4 sm[128];
  sm[t] = s;
  __syncthreads();
  if (rl == 0){
    float4 a = sm[cl], b = sm[32+cl], c4 = sm[64+cl], d = sm[96+cl];
    float4 vb = *reinterpret_cast<const float4*>(vn + (size_t)g*dgC + cq);
    float4 o;
    o.x = a.x+b.x+c4.x+d.x + vb.x;
    o.y = a.y+b.y+c4.y+d.y + vb.y;
    o.z = a.z+b.z+c4.z+d.z + vb.z;
    o.w = a.w+b.w+c4.w+d.w + vb.w;
    *reinterpret_cast<float4*>(vt + (size_t)g*dgC + cq) = o;
  }
}

__global__ __launch_bounds__(128)
void dg35_vt(const void* __restrict__ h2, const float* __restrict__ vn,
             const int* __restrict__ gs, float* __restrict__ vt, int af){
  int g = blockIdx.x, c = threadIdx.x;
  float s = 0.f;
  int r0 = gs[g], r1 = gs[g+1];
  for (int rr = r0; rr < r1; ++rr) s += dg35_ldx(h2, (size_t)rr*dgC + c, af);
  vt[g*dgC + c] = s + vn[g*dgC + c];
}

__global__ void dg35_vnfin(const float* __restrict__ z2, const float* __restrict__ ab,
                           float* __restrict__ vn){
  int i = blockIdx.x*256 + threadIdx.x;
  int c = i & (dgC-1);
  vn[i] = fmaxf(z2[i]*ab[c] + ab[dgC + c], 0.f);
}

__global__ void dg35_addvn4(float* __restrict__ h2, const float* __restrict__ vn,
                            const int* __restrict__ batch){
  int i = blockIdx.x*256 + threadIdx.x;
  int row = i >> 5;
  int cl = i & 31;
  float4 v = reinterpret_cast<float4*>(h2)[i];
  float4 a = reinterpret_cast<const float4*>(vn)[batch[row]*32 + cl];
  v.x += a.x; v.y += a.y; v.z += a.z; v.w += a.w;
  reinterpret_cast<float4*>(h2)[i] = v;
}

__global__ __launch_bounds__(128)
void dg35_addvn(void* __restrict__ h2, const float* __restrict__ vn,
                const int* __restrict__ batch, int af){
  int i = blockIdx.x, c = threadIdx.x;
  size_t idx = (size_t)i*dgC + c;
  dg35_stx(h2, idx, af, dg35_ldx(h2, idx, af) + vn[batch[i]*dgC + c]);
}

__global__ __launch_bounds__(128)
void dg35_out4(const float* __restrict__ h, const float* __restrict__ ab,
               const int* __restrict__ gs, float* __restrict__ out){
  int g = blockIdx.x, t = threadIdx.x;
  int rl = t >> 5, cl = t & 31;
  int cq = cl*4;
  int r0 = gs[g], r1 = gs[g+1];
  float4 s = make_float4(0.f,0.f,0.f,0.f);
  for (int rr = r0 + rl; rr < r1; rr += 4){
    float4 v = *reinterpret_cast<const float4*>(h + (size_t)rr*dgC + cq);
    s.x += v.x; s.y += v.y; s.z += v.z; s.w += v.w;
  }
  __shared__ float4 sm[128];
  sm[t] = s;
  __syncthreads();
  if (rl == 0){
    float4 a4 = sm[cl], b4 = sm[32+cl], c4 = sm[64+cl], d4 = sm[96+cl];
    float cnt = (float)(r1 - r0);
    float4 o;
    float S;
    S = a4.x+b4.x+c4.x+d4.x; o.x = ab[cq+0]*S + ab[dgC+cq+0]*cnt;
    S = a4.y+b4.y+c4.y+d4.y; o.y = ab[cq+1]*S + ab[dgC+cq+1]*cnt;
    S = a4.z+b4.z+c4.z+d4.z; o.z = ab[cq+2]*S + ab[dgC+cq+2]*cnt;
    S = a4.w+b4.w+c4.w+d4.w; o.w = ab[cq+3]*S + ab[dgC+cq+3]*cnt;
    *reinterpret_cast<float4*>(out + (size_t)g*dgC + cq) = o;
  }
}

// tier-B fallback pieces
__global__ __launch_bounds__(128)
void dg35_gb(const void* __restrict__ hin, const dg35_u32* __restrict__ packed,
             const int* __restrict__ off, const float* __restrict__ bemb,
             void* __restrict__ hh, int af){
  int i = blockIdx.x, c = threadIdx.x;
  int b0 = off[i], b1 = off[i+1];
  float m = -3.0e38f, s = 0.f, w = 0.f;
  for (int p = b0; p < b1; ++p){
    dg35_u32 pk = packed[p];
    int src = (int)(pk & 0x1FFFFu);
    float e = bemb[((pk>>17)&7)*dgC + c] + bemb[(8+((pk>>20)&7))*dgC + c]
            + bemb[(16+((pk>>23)&7))*dgC + c];
    float msg = fmaxf(dg35_ldx(hin, (size_t)src*dgC + c, af) + e, 0.f) + 1e-7f;
    float mn = fmaxf(m, msg);
    float sc = __expf(m - mn), t2 = __expf(msg - mn);
    s = s*sc + t2; w = w*sc + msg*t2; m = mn;
  }
  float agg = (b1 > b0) ? (w / (s + 1e-16f)) : 0.f;
  float self = dg35_ldx(hin, (size_t)i*dgC + c, af);
  dg35_stx(hh, (size_t)i*dgC + c, af, self + agg);
}

__global__ __launch_bounds__(128)
void dg35_out(const void* __restrict__ h, const float* __restrict__ ab,
              const int* __restrict__ gs, float* __restrict__ out, int af){
  int g = blockIdx.x, c = threadIdx.x;
  float a = ab[c], b = ab[dgC + c];
  float s = 0.f;
  int r0 = gs[g], r1 = gs[g+1];
  for (int rr = r0; rr < r1; ++rr) s += dg35_ldx(h, (size_t)rr*dgC + c, af)*a + b;
  out[g*dgC + c] = s;
}

static inline size_t dg35_al(size_t x){ return (x + 255) & ~(size_t)255; }

extern "C" void kernel_launch(void* const* d_in, const int* in_sizes, int n_in,
                              void* d_out, int out_size, void* d_ws, size_t ws_size,
                              hipStream_t stream)
{
  const int*   x     = (const int*)d_in[0];
  const int*   eattr = (const int*)d_in[1];
  const int*   eidx  = (const int*)d_in[2];
  const int*   batch = (const int*)d_in[3];
  const float* aemb  = (const float*)d_in[4];
  const float* bemb  = (const float*)d_in[5];
  const float* vne   = (const float*)d_in[6];
  const float* cW1   = (const float*)d_in[7];
  const float* cb1   = (const float*)d_in[8];
  const float* cg1   = (const float*)d_in[9];
  const float* cbb1  = (const float*)d_in[10];
  const float* cW2   = (const float*)d_in[11];
  const float* cb2   = (const float*)d_in[12];
  const float* ng    = (const float*)d_in[13];
  const float* nb    = (const float*)d_in[14];
  const float* vW1   = (const float*)d_in[15];
  const float* vb1   = (const float*)d_in[16];
  const float* vg1   = (const float*)d_in[17];
  const float* vbb1  = (const float*)d_in[18];
  const float* vW2   = (const float*)d_in[19];
  const float* vb2   = (const float*)d_in[20];
  const float* vg2   = (const float*)d_in[21];
  const float* vbb2  = (const float*)d_in[22];
  float* out = (float*)d_out;

  const int nsb = (dgN + 255) / 256;

  const size_t fixed =
      dg35_al(dgG*dgC*4)*4 +
      dg35_al(8*2*dgC2*4) + dg35_al(2*dgC2*4) +
      dg35_al(8*2*dgC*4) +
      dg35_al(4*dgC*4) +
      dg35_al(2*dgC*4)*3 +
      dg35_al(dgN*4)*2 + dg35_al((dgN+1)*4) +
      dg35_al((dgG+1)*4) +
      dg35_al((size_t)dgE*4) +
      dg35_al(7*256*128*2)*4 +
      dg35_al(512*dgC*4) +
      dg35_al(256*4)*2;
  int af = 0;
  size_t esz = 2;
  {
    size_t bigf = dg35_al((size_t)dgN*dgC*4)*2 + dg35_al((size_t)dgN*dgC2*4);
    if (bigf + fixed <= ws_size){ af = 1; esz = 4; }
  }

  char* base = (char*)d_ws;
  size_t o = 0;
  void* h  = (void*)(base + o); o += dg35_al((size_t)dgN*dgC*esz);
  void* hh = (void*)(base + o); o += dg35_al((size_t)dgN*dgC*esz);
  void* zb = (void*)(base + o); o += dg35_al((size_t)dgN*dgC2*esz);
  float* vn   = (float*)(base + o); o += dg35_al(dgG*dgC*4);
  float* vt   = (float*)(base + o); o += dg35_al(dgG*dgC*4);
  float* zv1  = (float*)(base + o); o += dg35_al(dgG*dgC*4);
  float* zv2  = (float*)(base + o); o += dg35_al(dgG*dgC*4);
  float* st1  = (float*)(base + o); o += dg35_al(8*2*dgC2*4);
  float* ab1  = (float*)(base + o); o += dg35_al(2*dgC2*4);
  float* stH  = (float*)(base + o); o += dg35_al(8*2*dgC*4);
  float* stVV = (float*)(base + o); o += dg35_al(4*dgC*4);
  float* abh  = (float*)(base + o); o += dg35_al(2*dgC*4);
  float* abv1 = (float*)(base + o); o += dg35_al(2*dgC*4);
  float* abv2 = (float*)(base + o); o += dg35_al(2*dgC*4);
  int* deg = (int*)(base + o); o += dg35_al(dgN*4);
  int* cur = (int*)(base + o); o += dg35_al(dgN*4);
  int* off = (int*)(base + o); o += dg35_al((dgN+1)*4);
  int* gs  = (int*)(base + o); o += dg35_al((dgG+1)*4);
  dg35_u32* packed = (dg35_u32*)(base + o); o += dg35_al((size_t)dgE*4);
  short* Wt1h = (short*)(base + o); o += dg35_al(7*256*128*2);
  short* Wt1l = (short*)(base + o); o += dg35_al(7*256*128*2);
  short* Wt2h = (short*)(base + o); o += dg35_al(7*256*128*2);
  short* Wt2l = (short*)(base + o); o += dg35_al(7*256*128*2);
  float* ecomb = (float*)(base + o); o += dg35_al(512*dgC*4);
  int* bsum = (int*)(base + o); o += dg35_al(256*4);
  int* boff = (int*)(base + o); o += dg35_al(256*4);

  if (o > ws_size){
    hipMemsetAsync(d_out, 0x7F, (size_t)out_size*4, stream);
    return;
  }
  float* stV1 = stVV;
  float* stV2 = stVV + 2*dgC;
  void* h2 = zb;
  void* z  = zb;

  // ---- per-call setup ----
  hipMemsetAsync(deg, 0, sizeof(int)*dgN, stream);
  dg35_count  <<<(dgE+255)/256, 256, 0, stream>>>(eidx + dgE, deg, dgE);
  dg35_s1     <<<nsb, 256, 0, stream>>>(deg, bsum, dgN);
  dg35_s2     <<<1, 256, 0, stream>>>(bsum, boff, nsb);
  dg35_s3     <<<nsb, 256, 0, stream>>>(deg, boff, off, cur, dgN);
  dg35_scatter<<<(dgE+255)/256, 256, 0, stream>>>(eidx, eattr, cur, packed, dgE);
  dg35_gstart <<<(dgG+256)/256, 256, 0, stream>>>(batch, gs, dgN, dgG);
  dg35_atom   <<<dgN, dgC, 0, stream>>>(x, aemb, vne, h, af);
  dg35_vninit <<<(dgG*dgC)/256, 256, 0, stream>>>(vne, vn);
  dg35_wconv  <<<1792, 256, 0, stream>>>(cW1, cW2, Wt1h, Wt1l, Wt2h, Wt2l);
  dg35_ecomb  <<<512, 128, 0, stream>>>(bemb, ecomb);

  if (af){
    const int grb = (dgN + 127) / 128;   // 391 row-blocks (BM=128)
    for (int l = 0; l < 7; ++l){
      const float* hin = (const float*)h;
      hipMemsetAsync(st1, 0, 8*2*dgC2*sizeof(float), stream);
      if (l > 0){
        dg35_fin<<<1, 256, 0, stream>>>(stH, ng + (l-1)*dgC, nb + (l-1)*dgC,
                                        abh, 1.f/dgN, dgC, 8);
        hipMemsetAsync(stVV, 0, 4*dgC*sizeof(float), stream);
        dg35_h24<<<(dgN*dgC/4)/256, 256, 0, stream>>>((const float*)h, abh, (float*)h2);
        dg35_vt4<<<dgG, 128, 0, stream>>>((const float*)h2, vn, gs, vt);
        dg35_gemm_v<<<dim3(16,2), 256, 0, stream>>>(vt, vW1 + (l-1)*dgC*dgC,
                                                    vb1 + (l-1)*dgC, (const float*)0,
                                                    zv1, dgG, dgC, dgC, 0);
        dg35_cs4<<<64, 256, 0, stream>>>(zv1, stV1, dgG, dgC);
        dg35_fin<<<1, 256, 0, stream>>>(stV1, vg1 + (l-1)*dgC, vbb1 + (l-1)*dgC,
                                        abv1, 1.f/dgG, dgC, 1);
        dg35_gemm_v<<<dim3(16,2), 256, 0, stream>>>(zv1, vW2 + (l-1)*dgC*dgC,
                                                    vb2 + (l-1)*dgC, abv1,
                                                    zv2, dgG, dgC, dgC, 1);
        dg35_cs4<<<64, 256, 0, stream>>>(zv2, stV2, dgG, dgC);
        dg35_fin<<<1, 256, 0, stream>>>(stV2, vg2 + (l-1)*dgC, vbb2 + (l-1)*dgC,
                                        abv2, 1.f/dgG, dgC, 1);
        dg35_vnfin<<<(dgG*dgC)/256, 256, 0, stream>>>(zv2, abv2, vn);
        dg35_addvn4<<<(dgN*dgC/4)/256, 256, 0, stream>>>((float*)h2, vn, batch);
        hin = (const float*)h2;
      }
      dg35_gb2<<<(dgN+3)/4, 256, 0, stream>>>(hin, packed, off, ecomb, (float*)hh);
      dg35_gemmx<<<dim3(4, grb), 256, 0, stream>>>((const float*)hh,
                                                   Wt1h + l*32768, Wt1l + l*32768,
                                                   cb1 + l*dgC2, (const float*)0,
                                                   (const float*)0, (float*)z, st1,
                                                   dgN, dgC, dgC2, 0, 0);
      dg35_fin<<<1, 256, 0, stream>>>(st1, cg1 + l*dgC2, cbb1 + l*dgC2,
                                      ab1, 1.f/dgN, dgC2, 8);
      hipMemsetAsync(stH, 0, 8*2*dgC*sizeof(float), stream);
      dg35_gemmx<<<dim3(2, grb), 256, 0, stream>>>((const float*)z,
                                                   Wt2h + l*32768, Wt2l + l*32768,
                                                   cb2 + l*dgC, ab1,
                                                   (l==0) ? (const float*)0 : (const float*)h,
                                                   (float*)h, stH,
                                                   dgN, dgC2, dgC, 1, (l==0)?0:1);
    }
    dg35_fin<<<1, 256, 0, stream>>>(stH, ng + 6*dgC, nb + 6*dgC, abh, 1.f/dgN, dgC, 8);
    dg35_out4<<<dgG, 128, 0, stream>>>((const float*)h, abh, gs, out);
  } else {
    // tier-B fallback (bf16 storage, VALU GEMM)
    const int gx = (dgN + 63) / 64;
    for (int l = 0; l < 7; ++l){
      dg35_zero<<<1, 512, 0, stream>>>(st1, stH, stV1, stV2);
      const void* hin = h;
      if (l > 0){
        dg35_colstats<<<128, 256, 0, stream>>>(h, stH, dgN, dgC, af);
        dg35_fin<<<1, 256, 0, stream>>>(stH, ng + (l-1)*dgC, nb + (l-1)*dgC,
                                        abh, 1.f/dgN, dgC, 1);
        dg35_h2<<<(dgN*dgC)/256, 256, 0, stream>>>(h, abh, h2, af);
        dg35_vt<<<dgG, dgC, 0, stream>>>(h2, vn, gs, vt, af);
        dg35_gemm_v<<<dim3(16,2), 256, 0, stream>>>(vt, vW1 + (l-1)*dgC*dgC,
                                                    vb1 + (l-1)*dgC, (const float*)0,
                                                    zv1, dgG, dgC, dgC, 0);
        dg35_cs4<<<64, 256, 0, stream>>>(zv1, stV1, dgG, dgC);
        dg35_fin<<<1, 256, 0, stream>>>(stV1, vg1 + (l-1)*dgC, vbb1 + (l-1)*dgC,
                                        abv1, 1.f/dgG, dgC, 1);
        dg35_gemm_v<<<dim3(16,2), 256, 0, stream>>>(zv1, vW2 + (l-1)*dgC*dgC,
                                                    vb2 + (l-1)*dgC, abv1,
                                                    zv2, dgG, dgC, dgC, 1);
        dg35_cs4<<<64, 256, 0, stream>>>(zv2, stV2, dgG, dgC);
        dg35_fin<<<1, 256, 0, stream>>>(stV2, vg2 + (l-1)*dgC, vbb2 + (l-1)*dgC,
                                        abv2, 1.f/dgG, dgC, 1);
        dg35_vnfin<<<(dgG*dgC)/256, 256, 0, stream>>>(zv2, abv2, vn);
        dg35_addvn<<<dgN, dgC, 0, stream>>>(h2, vn, batch, af);
        hin = h2;
      }
      dg35_gb<<<dgN, dgC, 0, stream>>>(hin, packed, off, bemb, hh, af);
      dg35_gemm_h<<<dim3(gx,4), 256, 0, stream>>>(hh, cW1 + l*dgC*dgC2,
                                                  cb1 + l*dgC2, (const float*)0,
                                                  (const void*)0, z,
                                                  dgN, dgC, dgC2, 0, 0, af);
      dg35_colstats<<<128, 256, 0, stream>>>(z, st1, dgN, dgC2, af);
      dg35_fin<<<1, 256, 0, stream>>>(st1, cg1 + l*dgC2, cbb1 + l*dgC2,
                                      ab1, 1.f/dgN, dgC2, 1);
      dg35_gemm_h<<<dim3(gx,2), 256, 0, stream>>>(z, cW2 + l*dgC2*dgC,
                                                  cb2 + l*dgC, ab1, h, h,
                                                  dgN, dgC2, dgC, 1, (l==0)?0:1, af);
    }
    hipMemsetAsync(stH, 0, sizeof(float)*2*dgC, stream);
    dg35_colstats<<<128, 256, 0, stream>>>(h, stH, dgN, dgC, af);
    dg35_fin<<<1, 256, 0, stream>>>(stH, ng + 6*dgC, nb + 6*dgC, abh, 1.f/dgN, dgC, 1);
    dg35_out<<<dgG, dgC, 0, stream>>>(h, abh, gs, out, af);
  }
}

// Round 14
// 1409.113 us; speedup vs baseline: 1.1213x; 1.1213x over previous
//
#include <hip/hip_runtime.h>

typedef unsigned short dg35_u16;
typedef unsigned int   dg35_u32;

constexpr int dgN  = 50000;
constexpr int dgE  = 400000;
constexpr int dgG  = 1024;
constexpr int dgC  = 128;
constexpr int dgC2 = 256;

typedef __attribute__((ext_vector_type(8))) short dg35_s8v;   // 8 bf16 (4 VGPR)
typedef __attribute__((ext_vector_type(4))) float dg35_f4v;   // MFMA acc

__device__ __forceinline__ float dg35_bf2f(dg35_u16 u){
  return __uint_as_float(((dg35_u32)u) << 16);
}
__device__ __forceinline__ dg35_u16 dg35_f2bf(float f){
  dg35_u32 u = __float_as_uint(f);
  u += 0x7FFFu + ((u >> 16) & 1u);
  return (dg35_u16)(u >> 16);
}
__device__ __forceinline__ float dg35_ldx(const void* p, size_t i, int af){
  return af ? ((const float*)p)[i] : dg35_bf2f(((const dg35_u16*)p)[i]);
}
__device__ __forceinline__ void dg35_stx(void* p, size_t i, int af, float v){
  if (af) ((float*)p)[i] = v; else ((dg35_u16*)p)[i] = dg35_f2bf(v);
}

// Symbol from the harness template; kept but never launched.
__global__ void DeeperGCN_35820027248884_kernel(){}

// ---------------- CSR build ----------------
__global__ void dg35_count(const int* __restrict__ dst, int* __restrict__ deg, int e){
  int j = blockIdx.x*256 + threadIdx.x;
  if (j < e) atomicAdd(&deg[dst[j]], 1);
}

__global__ void dg35_s1(const int* __restrict__ deg, int* __restrict__ bsum, int n){
  __shared__ int sm[256];
  int t = threadIdx.x, b = blockIdx.x;
  int idx = b*256 + t;
  sm[t] = (idx < n) ? deg[idx] : 0;
  __syncthreads();
  for (int s = 128; s > 0; s >>= 1){
    if (t < s) sm[t] += sm[t+s];
    __syncthreads();
  }
  if (t == 0) bsum[b] = sm[0];
}

__global__ void dg35_s2(const int* __restrict__ bsum, int* __restrict__ boff, int nb){
  __shared__ int sm[256];
  int t = threadIdx.x;
  int v = (t < nb) ? bsum[t] : 0;
  sm[t] = v;
  __syncthreads();
  for (int s = 1; s < 256; s <<= 1){
    int u = (t >= s) ? sm[t-s] : 0;
    __syncthreads();
    sm[t] += u;
    __syncthreads();
  }
  if (t < nb) boff[t] = sm[t] - v;
}

__global__ void dg35_s3(const int* __restrict__ deg, const int* __restrict__ boff,
                        int* __restrict__ off, int* __restrict__ cur, int n){
  __shared__ int sm[256];
  int t = threadIdx.x, b = blockIdx.x;
  int idx = b*256 + t;
  int v = (idx < n) ? deg[idx] : 0;
  sm[t] = v;
  __syncthreads();
  for (int s = 1; s < 256; s <<= 1){
    int u = (t >= s) ? sm[t-s] : 0;
    __syncthreads();
    sm[t] += u;
    __syncthreads();
  }
  if (idx < n){
    int e = boff[b] + sm[t] - v;
    off[idx] = e; cur[idx] = e;
  }
  if (idx == 0) off[n] = dgE;
}

__global__ void dg35_scatter(const int* __restrict__ ei, const int* __restrict__ ea,
                             int* __restrict__ cur, dg35_u32* __restrict__ packed, int e){
  int j = blockIdx.x*256 + threadIdx.x;
  if (j >= e) return;
  int s = ei[j], d = ei[e + j];
  dg35_u32 a0 = (dg35_u32)ea[3*j], a1 = (dg35_u32)ea[3*j+1], a2 = (dg35_u32)ea[3*j+2];
  int pos = atomicAdd(&cur[d], 1);
  packed[pos] = (dg35_u32)s | (a0<<17) | (a1<<20) | (a2<<23);
}

__global__ void dg35_gstart(const int* __restrict__ batch, int* __restrict__ gs, int n, int g){
  int i = blockIdx.x*256 + threadIdx.x;
  if (i > g) return;
  if (i == g){ gs[i] = n; return; }
  int lo = 0, hi = n;
  while (lo < hi){ int mid = (lo+hi)>>1; if (batch[mid] < i) lo = mid+1; else hi = mid; }
  gs[i] = lo;
}

// ---------------- encoders / weight prep ----------------
__global__ __launch_bounds__(128)
void dg35_atom(const int* __restrict__ x, const float* __restrict__ aemb,
               const float* __restrict__ vne, void* __restrict__ h, int af){
  int i = blockIdx.x, c = threadIdx.x;
  float acc = vne[c];
  #pragma unroll
  for (int f = 0; f < 9; ++f){
    int idx = x[i*9 + f];
    acc += aemb[(f*128 + idx)*dgC + c];
  }
  dg35_stx(h, (size_t)i*dgC + c, af, acc);
}

__global__ void dg35_vninit(const float* __restrict__ vne, float* __restrict__ vn){
  int i = blockIdx.x*256 + threadIdx.x;
  if (i < dgG*dgC) vn[i] = vne[i & (dgC-1)];
}

// combo table: ecomb[c9][c] = bemb[a0][c] + bemb[8+a1][c] + bemb[16+a2][c]
__global__ __launch_bounds__(128)
void dg35_ecomb(const float* __restrict__ bemb, float* __restrict__ ecomb){
  int c9 = blockIdx.x, t = threadIdx.x;
  int a0 = c9 & 7, a1 = (c9 >> 3) & 7, a2 = (c9 >> 6) & 7;
  ecomb[c9*dgC + t] = bemb[a0*dgC + t] + bemb[(8+a1)*dgC + t] + bemb[(16+a2)*dgC + t];
}

// transpose+convert conv weights to SPLIT bf16 (hi+lo) in [l][n][k] layout
__global__ void dg35_wconv(const float* __restrict__ W1, const float* __restrict__ W2,
                           short* __restrict__ Wt1h, short* __restrict__ Wt1l,
                           short* __restrict__ Wt2h, short* __restrict__ Wt2l){
  int i = blockIdx.x*256 + threadIdx.x;
  constexpr int per = 7*256*128;
  float w;
  short* ph; short* pl; int oidx;
  if (i < per){
    int l = i >> 15;
    int rem = i & 32767;
    int n = rem >> 7;
    int k = rem & 127;
    w = W1[l*32768 + k*256 + n];
    ph = Wt1h; pl = Wt1l; oidx = i;
  } else {
    int j = i - per;
    int l = j >> 15;
    int rem = j & 32767;
    int n = rem >> 8;
    int k = rem & 255;
    w = W2[l*32768 + k*128 + n];
    ph = Wt2h; pl = Wt2l; oidx = j;
  }
  dg35_u16 hi = dg35_f2bf(w);
  float lo = w - dg35_bf2f(hi);
  ph[oidx] = (short)hi;
  pl[oidx] = (short)dg35_f2bf(lo);
}

__global__ void dg35_zero(float* a, float* b, float* c_, float* d){
  int t = threadIdx.x;
  if (t < 512) a[t] = 0.f;
  if (t < 256){ b[t]=0.f; c_[t]=0.f; d[t]=0.f; }
}

// ------------- GENConv softmax aggr: exp-direct (shift-8), 2 ch/lane, 2 edge streams ----
// msg = relu(h+e)+1e-7 is BN-bounded (<< 80), so exp(msg-8) cannot overflow; the
// constant shift cancels exactly in w/s. No running max -> 4 VALU ops per update.
__global__ __launch_bounds__(256)
void dg35_gb2(const float* __restrict__ hin, const dg35_u32* __restrict__ packed,
              const int* __restrict__ off, const float* __restrict__ ecomb,
              float* __restrict__ hh){
  int i = blockIdx.x*4 + (threadIdx.x >> 6);
  if (i >= dgN) return;
  int c = (threadIdx.x & 63) * 2;
  int b0 = off[i], b1 = off[i+1];
  float2 self = *reinterpret_cast<const float2*>(hin + (size_t)i*dgC + c);
  float sA0=0.f, wA0=0.f, sA1=0.f, wA1=0.f;
  float sB0=0.f, wB0=0.f, sB1=0.f, wB1=0.f;
  int p = b0;
  for (; p + 1 < b1; p += 2){
    dg35_u32 pkA = packed[p], pkB = packed[p+1];
    int srcA = (int)(pkA & 0x1FFFFu), srcB = (int)(pkB & 0x1FFFFu);
    float2 hA = *reinterpret_cast<const float2*>(hin + (size_t)srcA*dgC + c);
    float2 hB = *reinterpret_cast<const float2*>(hin + (size_t)srcB*dgC + c);
    float2 eA = *reinterpret_cast<const float2*>(ecomb + (size_t)(pkA>>17)*dgC + c);
    float2 eB = *reinterpret_cast<const float2*>(ecomb + (size_t)(pkB>>17)*dgC + c);
    float msgA0 = fmaxf(hA.x + eA.x, 0.f) + 1e-7f;
    float msgA1 = fmaxf(hA.y + eA.y, 0.f) + 1e-7f;
    float msgB0 = fmaxf(hB.x + eB.x, 0.f) + 1e-7f;
    float msgB1 = fmaxf(hB.y + eB.y, 0.f) + 1e-7f;
    float tA0 = __expf(msgA0 - 8.f), tA1 = __expf(msgA1 - 8.f);
    float tB0 = __expf(msgB0 - 8.f), tB1 = __expf(msgB1 - 8.f);
    sA0 += tA0; wA0 = fmaf(msgA0, tA0, wA0);
    sA1 += tA1; wA1 = fmaf(msgA1, tA1, wA1);
    sB0 += tB0; wB0 = fmaf(msgB0, tB0, wB0);
    sB1 += tB1; wB1 = fmaf(msgB1, tB1, wB1);
  }
  if (p < b1){
    dg35_u32 pkA = packed[p];
    int srcA = (int)(pkA & 0x1FFFFu);
    float2 hA = *reinterpret_cast<const float2*>(hin + (size_t)srcA*dgC + c);
    float2 eA = *reinterpret_cast<const float2*>(ecomb + (size_t)(pkA>>17)*dgC + c);
    float msg0 = fmaxf(hA.x + eA.x, 0.f) + 1e-7f;
    float msg1 = fmaxf(hA.y + eA.y, 0.f) + 1e-7f;
    float t0 = __expf(msg0 - 8.f), t1 = __expf(msg1 - 8.f);
    sA0 += t0; wA0 = fmaf(msg0, t0, wA0);
    sA1 += t1; wA1 = fmaf(msg1, t1, wA1);
  }
  float s0 = sA0 + sB0, w0 = wA0 + wB0;
  float s1 = sA1 + sB1, w1 = wA1 + wB1;
  float2 o;
  o.x = self.x + ((b1 > b0) ? (w0 / (s0 + 1e-16f)) : 0.f);
  o.y = self.y + ((b1 > b0) ? (w1 / (s1 + 1e-16f)) : 0.f);
  *reinterpret_cast<float2*>(hh + (size_t)i*dgC + c) = o;
}

// ---- split-bf16 MFMA GEMM, BM=64, A+B both LDS-staged (swizzled), prefetch,
//      fused column stats with 8-way replicated accumulators, XCD chunk swizzle ----
// (round-12 configuration: 32 KB LDS, 5 blocks/CU — best measured)
__global__ __launch_bounds__(256)
void dg35_gemmx(const float* __restrict__ A, const short* __restrict__ Whi,
                const short* __restrict__ Wlo, const float* __restrict__ bias,
                const float* __restrict__ ab, const float* __restrict__ res,
                float* __restrict__ Cout, float* __restrict__ st,
                int M, int K, int NC, int trans, int addres){
  __shared__ short Ahi[64*64];   // 8 KB
  __shared__ short Alo[64*64];   // 8 KB
  __shared__ short Bhs[64*64];   // 8 KB
  __shared__ short Bls[64*64];   // 8 KB
  int tid = threadIdx.x;
  // bijective XCD chunk swizzle (m204)
  int nwg = gridDim.x * gridDim.y;
  int lin = blockIdx.y * gridDim.x + blockIdx.x;
  int q8 = nwg >> 3, r8 = nwg & 7;
  int xcd = lin & 7, pos = lin >> 3;
  int wg = (xcd < r8) ? (xcd*(q8+1) + pos) : (r8*(q8+1) + (xcd-r8)*q8 + pos);
  int bn = (wg % gridDim.x) * 64;
  int bm = (wg / gridDim.x) * 64;
  float* stc = st + (size_t)(wg & 7) * 2 * NC;
  int lane = tid & 63;
  int wv = tid >> 6;
  int l15 = lane & 15;
  int l4  = lane >> 4;
  dg35_f4v acc[4] = {};

  int r = tid >> 2;            // A staging row 0..63
  int cq = (tid & 3) * 16;     // 16 f32 per thread
  int grow = bm + r;
  int swbase = cq >> 3;
  // B staging coords
  int nB = tid >> 2;
  int kqB = (tid & 3) * 16;
  const short* wbase_h = Whi + (size_t)(bn + nB)*K + kqB;
  const short* wbase_l = Wlo + (size_t)(bn + nB)*K + kqB;

  float4 va[4];
  {
    const float* ap = A + (size_t)grow*K + cq;
    if (grow < M){
      #pragma unroll
      for (int q2 = 0; q2 < 4; ++q2) va[q2] = *reinterpret_cast<const float4*>(ap + q2*4);
    } else {
      #pragma unroll
      for (int q2 = 0; q2 < 4; ++q2) va[q2] = make_float4(0.f,0.f,0.f,0.f);
    }
  }

  for (int k0 = 0; k0 < K; k0 += 64){
    // issue B loads (latency overlaps A conversion)
    uint4 bth[2], btl[2];
    #pragma unroll
    for (int j = 0; j < 2; ++j){
      bth[j] = *reinterpret_cast<const uint4*>(wbase_h + k0 + j*8);
      btl[j] = *reinterpret_cast<const uint4*>(wbase_l + k0 + j*8);
    }
    // convert current A tile -> swizzled split-bf16 LDS
    {
      float xv[16];
      #pragma unroll
      for (int q2 = 0; q2 < 4; ++q2){
        xv[q2*4+0]=va[q2].x; xv[q2*4+1]=va[q2].y;
        xv[q2*4+2]=va[q2].z; xv[q2*4+3]=va[q2].w;
      }
      if (trans){
        #pragma unroll
        for (int q2 = 0; q2 < 16; ++q2){
          int kk = k0 + cq + q2;
          xv[q2] = fmaxf(xv[q2]*ab[kk] + ab[K + kk], 0.f);
        }
      }
      #pragma unroll
      for (int g = 0; g < 2; ++g){
        uint4 wh, wl;
        unsigned* hp = (unsigned*)&wh;
        unsigned* lp = (unsigned*)&wl;
        #pragma unroll
        for (int d = 0; d < 4; ++d){
          float f0 = xv[g*8 + d*2], f1 = xv[g*8 + d*2 + 1];
          dg35_u16 h0 = dg35_f2bf(f0), h1 = dg35_f2bf(f1);
          dg35_u16 l0 = dg35_f2bf(f0 - dg35_bf2f(h0));
          dg35_u16 l1 = dg35_f2bf(f1 - dg35_bf2f(h1));
          hp[d] = (dg35_u32)h0 | ((dg35_u32)h1 << 16);
          lp[d] = (dg35_u32)l0 | ((dg35_u32)l1 << 16);
        }
        int slot = (swbase + g) ^ (r & 7);
        *reinterpret_cast<uint4*>(&Ahi[r*64 + slot*8]) = wh;
        *reinterpret_cast<uint4*>(&Alo[r*64 + slot*8]) = wl;
      }
    }
    // write B to swizzled LDS
    #pragma unroll
    for (int j = 0; j < 2; ++j){
      int slot = ((kqB >> 3) + j) ^ (nB & 7);
      *reinterpret_cast<uint4*>(&Bhs[nB*64 + slot*8]) = bth[j];
      *reinterpret_cast<uint4*>(&Bls[nB*64 + slot*8]) = btl[j];
    }
    __syncthreads();
    // prefetch next A tile (overlaps MFMA below)
    if (k0 + 64 < K && grow < M){
      const float* ap = A + (size_t)grow*K + k0 + 64 + cq;
      #pragma unroll
      for (int q2 = 0; q2 < 4; ++q2) va[q2] = *reinterpret_cast<const float4*>(ap + q2*4);
    }
    // MFMA over 2 K-steps of 32, A and B both from LDS
    #pragma unroll
    for (int ks = 0; ks < 2; ++ks){
      dg35_s8v bh[4], bl[4];
      #pragma unroll
      for (int nf = 0; nf < 4; ++nf){
        int n = nf*16 + l15;
        int slot = (ks*4 + l4) ^ (n & 7);
        bh[nf] = *reinterpret_cast<const dg35_s8v*>(&Bhs[n*64 + slot*8]);
        bl[nf] = *reinterpret_cast<const dg35_s8v*>(&Bls[n*64 + slot*8]);
      }
      int row = wv*16 + l15;
      int slotA = (ks*4 + l4) ^ (row & 7);
      dg35_s8v ah = *reinterpret_cast<const dg35_s8v*>(&Ahi[row*64 + slotA*8]);
      dg35_s8v al = *reinterpret_cast<const dg35_s8v*>(&Alo[row*64 + slotA*8]);
      #pragma unroll
      for (int nf = 0; nf < 4; ++nf){
        acc[nf] = __builtin_amdgcn_mfma_f32_16x16x32_bf16(ah, bh[nf], acc[nf], 0, 0, 0);
        acc[nf] = __builtin_amdgcn_mfma_f32_16x16x32_bf16(al, bh[nf], acc[nf], 0, 0, 0);
        acc[nf] = __builtin_amdgcn_mfma_f32_16x16x32_bf16(ah, bl[nf], acc[nf], 0, 0, 0);
      }
    }
    __syncthreads();
  }
  // epilogue: write + per-lane col partial stats
  float s[4] = {0.f,0.f,0.f,0.f}, q[4] = {0.f,0.f,0.f,0.f};
  #pragma unroll
  for (int e = 0; e < 4; ++e){
    int rr = bm + wv*16 + l4*4 + e;
    if (rr >= M) continue;
    #pragma unroll
    for (int nf = 0; nf < 4; ++nf){
      int cc = bn + nf*16 + l15;
      float v = acc[nf][e] + bias[cc];
      size_t idx = (size_t)rr*NC + cc;
      if (addres) v += res[idx];
      Cout[idx] = v;
      s[nf] += v; q[nf] += v*v;
    }
  }
  #pragma unroll
  for (int nf = 0; nf < 4; ++nf){
    s[nf] += __shfl_xor(s[nf], 16); s[nf] += __shfl_xor(s[nf], 32);
    q[nf] += __shfl_xor(q[nf], 16); q[nf] += __shfl_xor(q[nf], 32);
  }
  __syncthreads();
  float* red = (float*)Ahi;
  if (l4 == 0){
    #pragma unroll
    for (int nf = 0; nf < 4; ++nf){
      red[wv*128 + nf*16 + l15] = s[nf];
      red[wv*128 + 64 + nf*16 + l15] = q[nf];
    }
  }
  __syncthreads();
  if (tid < 64){
    float S = red[tid] + red[128+tid] + red[256+tid] + red[384+tid];
    float Q = red[64+tid] + red[192+tid] + red[320+tid] + red[448+tid];
    atomicAdd(&stc[bn + tid], S);
    atomicAdd(&stc[NC + bn + tid], Q);
  }
}

// -------- VALU GEMM (dual-precision) — tier-B fallback only --------
__global__ __launch_bounds__(256)
void dg35_gemm_h(const void* __restrict__ A, const float* __restrict__ W,
                 const float* __restrict__ bias, const float* __restrict__ ab,
                 const void* __restrict__ res, void* __restrict__ Cout,
                 int M, int K, int NC, int trans, int addres, int af){
  __shared__ float At[32][65];
  __shared__ float Bt[32][64];
  int bm = blockIdx.x * 64;
  int bn = blockIdx.y * 64;
  int tid = threadIdx.x;
  int tx = tid & 15, ty = tid >> 4;
  float acc[4][4];
  #pragma unroll
  for (int i2 = 0; i2 < 4; ++i2)
    #pragma unroll
    for (int j2 = 0; j2 < 4; ++j2) acc[i2][j2] = 0.f;

  for (int k0 = 0; k0 < K; k0 += 32){
    int r = tid >> 3;
    int kq = (tid & 7) * 4;
    #pragma unroll
    for (int half = 0; half < 2; ++half){
      int rr = r + half*32;
      int grow = bm + rr;
      float vv[4] = {0.f, 0.f, 0.f, 0.f};
      if (grow < M){
        if (af){
          float4 v4 = *reinterpret_cast<const float4*>((const float*)A + (size_t)grow*K + k0 + kq);
          vv[0] = v4.x; vv[1] = v4.y; vv[2] = v4.z; vv[3] = v4.w;
        } else {
          ushort4 v4 = *reinterpret_cast<const ushort4*>((const dg35_u16*)A + (size_t)grow*K + k0 + kq);
          vv[0] = dg35_bf2f(v4.x); vv[1] = dg35_bf2f(v4.y);
          vv[2] = dg35_bf2f(v4.z); vv[3] = dg35_bf2f(v4.w);
        }
      }
      #pragma unroll
      for (int i2 = 0; i2 < 4; ++i2){
        float xv = vv[i2];
        if (trans){
          int kk = k0 + kq + i2;
          xv = fmaxf(xv*ab[kk] + ab[K + kk], 0.f);
        }
        At[kq + i2][rr] = xv;
      }
    }
    {
      int kr = tid >> 3;
      int cq = (tid & 7) * 8;
      const float* wp = W + (size_t)(k0 + kr)*NC + bn + cq;
      #pragma unroll
      for (int i2 = 0; i2 < 8; ++i2) Bt[kr][cq + i2] = wp[i2];
    }
    __syncthreads();
    #pragma unroll
    for (int kk = 0; kk < 32; ++kk){
      float a4[4], b4[4];
      #pragma unroll
      for (int i2 = 0; i2 < 4; ++i2) a4[i2] = At[kk][ty*4 + i2];
      #pragma unroll
      for (int j2 = 0; j2 < 4; ++j2) b4[j2] = Bt[kk][tx*4 + j2];
      #pragma unroll
      for (int i2 = 0; i2 < 4; ++i2)
        #pragma unroll
        for (int j2 = 0; j2 < 4; ++j2)
          acc[i2][j2] += a4[i2]*b4[j2];
    }
    __syncthreads();
  }
  #pragma unroll
  for (int i2 = 0; i2 < 4; ++i2){
    int rr = bm + ty*4 + i2;
    if (rr >= M) continue;
    #pragma unroll
    for (int j2 = 0; j2 < 4; ++j2){
      int cc = bn + tx*4 + j2;
      float v = acc[i2][j2] + bias[cc];
      size_t idx = (size_t)rr*NC + cc;
      if (addres) v += dg35_ldx(res, idx, af);
      dg35_stx(Cout, idx, af, v);
    }
  }
}

// -------- GEMM, A f32, W f32, f32 out (virtual-node MLP, M=1024) --------
__global__ __launch_bounds__(256)
void dg35_gemm_v(const float* __restrict__ A, const float* __restrict__ W,
                 const float* __restrict__ bias, const float* __restrict__ ab,
                 float* __restrict__ Cout, int M, int K, int NC, int trans){
  __shared__ float At[32][65];
  __shared__ float Bt[32][64];
  int bm = blockIdx.x * 64;
  int bn = blockIdx.y * 64;
  int tid = threadIdx.x;
  int tx = tid & 15, ty = tid >> 4;
  float acc[4][4];
  #pragma unroll
  for (int i2 = 0; i2 < 4; ++i2)
    #pragma unroll
    for (int j2 = 0; j2 < 4; ++j2) acc[i2][j2] = 0.f;

  for (int k0 = 0; k0 < K; k0 += 32){
    int r = tid >> 3;
    int kq = (tid & 7) * 4;
    #pragma unroll
    for (int half = 0; half < 2; ++half){
      int rr = r + half*32;
      int grow = bm + rr;
      float vv[4] = {0.f, 0.f, 0.f, 0.f};
      if (grow < M){
        float4 v4 = *reinterpret_cast<const float4*>(A + (size_t)grow*K + k0 + kq);
        vv[0] = v4.x; vv[1] = v4.y; vv[2] = v4.z; vv[3] = v4.w;
      }
      #pragma unroll
      for (int i2 = 0; i2 < 4; ++i2){
        float xv = vv[i2];
        if (trans){
          int kk = k0 + kq + i2;
          xv = fmaxf(xv*ab[kk] + ab[K + kk], 0.f);
        }
        At[kq + i2][rr] = xv;
      }
    }
    {
      int kr = tid >> 3;
      int cq = (tid & 7) * 8;
      const float* wp = W + (size_t)(k0 + kr)*NC + bn + cq;
      #pragma unroll
      for (int i2 = 0; i2 < 8; ++i2) Bt[kr][cq + i2] = wp[i2];
    }
    __syncthreads();
    #pragma unroll
    for (int kk = 0; kk < 32; ++kk){
      float a4[4], b4[4];
      #pragma unroll
      for (int i2 = 0; i2 < 4; ++i2) a4[i2] = At[kk][ty*4 + i2];
      #pragma unroll
      for (int j2 = 0; j2 < 4; ++j2) b4[j2] = Bt[kk][tx*4 + j2];
      #pragma unroll
      for (int i2 = 0; i2 < 4; ++i2)
        #pragma unroll
        for (int j2 = 0; j2 < 4; ++j2)
          acc[i2][j2] += a4[i2]*b4[j2];
    }
    __syncthreads();
  }
  #pragma unroll
  for (int i2 = 0; i2 < 4; ++i2){
    int rr = bm + ty*4 + i2;
    if (rr >= M) continue;
    #pragma unroll
    for (int j2 = 0; j2 < 4; ++j2){
      int cc = bn + tx*4 + j2;
      Cout[(size_t)rr*NC + cc] = acc[i2][j2] + bias[cc];
    }
  }
}

// ---------------- BN statistics (small f32 buffers: zv1/zv2) ----------------
__global__ __launch_bounds__(256)
void dg35_cs4(const float* __restrict__ Z, float* __restrict__ st, int n, int ncols){
  int t = threadIdx.x;
  int lpr = ncols >> 2;
  int rl = t / lpr;
  int rpb = 256 / lpr;
  int cq = (t - rl*lpr) * 4;
  float4 s = make_float4(0.f,0.f,0.f,0.f);
  float4 q = make_float4(0.f,0.f,0.f,0.f);
  for (int rr = blockIdx.x*rpb + rl; rr < n; rr += gridDim.x*rpb){
    float4 v = *reinterpret_cast<const float4*>(Z + (size_t)rr*ncols + cq);
    s.x += v.x; s.y += v.y; s.z += v.z; s.w += v.w;
    q.x += v.x*v.x; q.y += v.y*v.y; q.z += v.z*v.z; q.w += v.w*v.w;
  }
  __shared__ float sm[256*8];
  float* my = &sm[t*8];
  my[0]=s.x; my[1]=s.y; my[2]=s.z; my[3]=s.w;
  my[4]=q.x; my[5]=q.y; my[6]=q.z; my[7]=q.w;
  __syncthreads();
  if (rl == 0){
    float a[8];
    #pragma unroll
    for (int d = 0; d < 8; ++d) a[d] = my[d];
    for (int j = 1; j < rpb; ++j){
      const float* o2 = &sm[(t + j*lpr)*8];
      #pragma unroll
      for (int d = 0; d < 8; ++d) a[d] += o2[d];
    }
    #pragma unroll
    for (int d = 0; d < 4; ++d) atomicAdd(&st[cq + d], a[d]);
    #pragma unroll
    for (int d = 0; d < 4; ++d) atomicAdd(&st[ncols + cq + d], a[4 + d]);
  }
}

// tier-B fallback colstats
__global__ void dg35_colstats(const void* __restrict__ Z, float* __restrict__ st,
                              int n, int ncols, int af){
  int tid = threadIdx.x;
  int c = tid & (ncols - 1);
  int rl = tid / ncols;
  int rpb = 256 / ncols;
  float s = 0.f, q = 0.f;
  for (int rr = blockIdx.x*rpb + rl; rr < n; rr += gridDim.x*rpb){
    float v = dg35_ldx(Z, (size_t)rr*ncols + c, af);
    s += v; q += v*v;
  }
  atomicAdd(&st[c], s);
  atomicAdd(&st[ncols + c], q);
}

// finalize BN affine from (possibly replicated) stats
__global__ void dg35_fin(const float* __restrict__ st, const float* __restrict__ g,
                         const float* __restrict__ b, float* __restrict__ ab,
                         float inv_n, int ncols, int ncopy){
  int c = threadIdx.x + blockIdx.x*256;
  if (c >= ncols) return;
  float m = 0.f, q = 0.f;
  for (int k = 0; k < ncopy; ++k){
    m += st[(size_t)k*2*ncols + c];
    q += st[(size_t)k*2*ncols + ncols + c];
  }
  m *= inv_n;
  float var = q*inv_n - m*m;
  float rstd = rsqrtf(var + 1e-5f);
  float a = g[c]*rstd;
  ab[c] = a;
  ab[ncols + c] = b[c] - m*a;
}

// ---------------- elementwise / segment ops ----------------
__global__ void dg35_h24(const float* __restrict__ h, const float* __restrict__ ab,
                         float* __restrict__ h2){
  int i = blockIdx.x*256 + threadIdx.x;
  int c = (i & 31) * 4;
  float4 v = reinterpret_cast<const float4*>(h)[i];
  v.x = fmaxf(v.x*ab[c+0] + ab[dgC+c+0], 0.f);
  v.y = fmaxf(v.y*ab[c+1] + ab[dgC+c+1], 0.f);
  v.z = fmaxf(v.z*ab[c+2] + ab[dgC+c+2], 0.f);
  v.w = fmaxf(v.w*ab[c+3] + ab[dgC+c+3], 0.f);
  reinterpret_cast<float4*>(h2)[i] = v;
}

__global__ void dg35_h2(const void* __restrict__ h, const float* __restrict__ ab,
                        void* __restrict__ h2, int af){
  int i = blockIdx.x*256 + threadIdx.x;
  int c = i & (dgC-1);
  dg35_stx(h2, i, af, fmaxf(dg35_ldx(h, i, af)*ab[c] + ab[dgC + c], 0.f));
}

__global__ __launch_bounds__(128)
void dg35_vt4(const float* __restrict__ h2, const float* __restrict__ vn,
              const int* __restrict__ gs, float* __restrict__ vt){
  int g = blockIdx.x, t = threadIdx.x;
  int rl = t >> 5, cl = t & 31;
  int cq = cl*4;
  int r0 = gs[g], r1 = gs[g+1];
  float4 s = make_float4(0.f,0.f,0.f,0.f);
  for (int rr = r0 + rl; rr < r1; rr += 4){
    float4 v = *reinterpret_cast<const float4*>(h2 + (size_t)rr*dgC + cq);
    s.x += v.x; s.y += v.y; s.z += v.z; s.w += v.w;
  }
  __shared__ float4 sm[128];
  sm[t] = s;
  __syncthreads();
  if (rl == 0){
    float4 a = sm[cl], b = sm[32+cl], c4 = sm[64+cl], d = sm[96+cl];
    float4 vb = *reinterpret_cast<const float4*>(vn + (size_t)g*dgC + cq);
    float4 o;
    o.x = a.x+b.x+c4.x+d.x + vb.x;
    o.y = a.y+b.y+c4.y+d.y + vb.y;
    o.z = a.z+b.z+c4.z+d.z + vb.z;
    o.w = a.w+b.w+c4.w+d.w + vb.w;
    *reinterpret_cast<float4*>(vt + (size_t)g*dgC + cq) = o;
  }
}

__global__ __launch_bounds__(128)
void dg35_vt(const void* __restrict__ h2, const float* __restrict__ vn,
             const int* __restrict__ gs, float* __restrict__ vt, int af){
  int g = blockIdx.x, c = threadIdx.x;
  float s = 0.f;
  int r0 = gs[g], r1 = gs[g+1];
  for (int rr = r0; rr < r1; ++rr) s += dg35_ldx(h2, (size_t)rr*dgC + c, af);
  vt[g*dgC + c] = s + vn[g*dgC + c];
}

__global__ void dg35_vnfin(const float* __restrict__ z2, const float* __restrict__ ab,
                           float* __restrict__ vn){
  int i = blockIdx.x*256 + threadIdx.x;
  int c = i & (dgC-1);
  vn[i] = fmaxf(z2[i]*ab[c] + ab[dgC + c], 0.f);
}

__global__ void dg35_addvn4(float* __restrict__ h2, const float* __restrict__ vn,
                            const int* __restrict__ batch){
  int i = blockIdx.x*256 + threadIdx.x;
  int row = i >> 5;
  int cl = i & 31;
  float4 v = reinterpret_cast<float4*>(h2)[i];
  float4 a = reinterpret_cast<const float4*>(vn)[batch[row]*32 + cl];
  v.x += a.x; v.y += a.y; v.z += a.z; v.w += a.w;
  reinterpret_cast<float4*>(h2)[i] = v;
}

__global__ __launch_bounds__(128)
void dg35_addvn(void* __restrict__ h2, const float* __restrict__ vn,
                const int* __restrict__ batch, int af){
  int i = blockIdx.x, c = threadIdx.x;
  size_t idx = (size_t)i*dgC + c;
  dg35_stx(h2, idx, af, dg35_ldx(h2, idx, af) + vn[batch[i]*dgC + c]);
}

__global__ __launch_bounds__(128)
void dg35_out4(const float* __restrict__ h, const float* __restrict__ ab,
               const int* __restrict__ gs, float* __restrict__ out){
  int g = blockIdx.x, t = threadIdx.x;
  int rl = t >> 5, cl = t & 31;
  int cq = cl*4;
  int r0 = gs[g], r1 = gs[g+1];
  float4 s = make_float4(0.f,0.f,0.f,0.f);
  for (int rr = r0 + rl; rr < r1; rr += 4){
    float4 v = *reinterpret_cast<const float4*>(h + (size_t)rr*dgC + cq);
    s.x += v.x; s.y += v.y; s.z += v.z; s.w += v.w;
  }
  __shared__ float4 sm[128];
  sm[t] = s;
  __syncthreads();
  if (rl == 0){
    float4 a4 = sm[cl], b4 = sm[32+cl], c4 = sm[64+cl], d4 = sm[96+cl];
    float cnt = (float)(r1 - r0);
    float4 o;
    float S;
    S = a4.x+b4.x+c4.x+d4.x; o.x = ab[cq+0]*S + ab[dgC+cq+0]*cnt;
    S = a4.y+b4.y+c4.y+d4.y; o.y = ab[cq+1]*S + ab[dgC+cq+1]*cnt;
    S = a4.z+b4.z+c4.z+d4.z; o.z = ab[cq+2]*S + ab[dgC+cq+2]*cnt;
    S = a4.w+b4.w+c4.w+d4.w; o.w = ab[cq+3]*S + ab[dgC+cq+3]*cnt;
    *reinterpret_cast<float4*>(out + (size_t)g*dgC + cq) = o;
  }
}

// tier-B fallback pieces
__global__ __launch_bounds__(128)
void dg35_gb(const void* __restrict__ hin, const dg35_u32* __restrict__ packed,
             const int* __restrict__ off, const float* __restrict__ bemb,
             void* __restrict__ hh, int af){
  int i = blockIdx.x, c = threadIdx.x;
  int b0 = off[i], b1 = off[i+1];
  float m = -3.0e38f, s = 0.f, w = 0.f;
  for (int p = b0; p < b1; ++p){
    dg35_u32 pk = packed[p];
    int src = (int)(pk & 0x1FFFFu);
    float e = bemb[((pk>>17)&7)*dgC + c] + bemb[(8+((pk>>20)&7))*dgC + c]
            + bemb[(16+((pk>>23)&7))*dgC + c];
    float msg = fmaxf(dg35_ldx(hin, (size_t)src*dgC + c, af) + e, 0.f) + 1e-7f;
    float mn = fmaxf(m, msg);
    float sc = __expf(m - mn), t2 = __expf(msg - mn);
    s = s*sc + t2; w = w*sc + msg*t2; m = mn;
  }
  float agg = (b1 > b0) ? (w / (s + 1e-16f)) : 0.f;
  float self = dg35_ldx(hin, (size_t)i*dgC + c, af);
  dg35_stx(hh, (size_t)i*dgC + c, af, self + agg);
}

__global__ __launch_bounds__(128)
void dg35_out(const void* __restrict__ h, const float* __restrict__ ab,
              const int* __restrict__ gs, float* __restrict__ out, int af){
  int g = blockIdx.x, c = threadIdx.x;
  float a = ab[c], b = ab[dgC + c];
  float s = 0.f;
  int r0 = gs[g], r1 = gs[g+1];
  for (int rr = r0; rr < r1; ++rr) s += dg35_ldx(h, (size_t)rr*dgC + c, af)*a + b;
  out[g*dgC + c] = s;
}

static inline size_t dg35_al(size_t x){ return (x + 255) & ~(size_t)255; }

extern "C" void kernel_launch(void* const* d_in, const int* in_sizes, int n_in,
                              void* d_out, int out_size, void* d_ws, size_t ws_size,
                              hipStream_t stream)
{
  const int*   x     = (const int*)d_in[0];
  const int*   eattr = (const int*)d_in[1];
  const int*   eidx  = (const int*)d_in[2];
  const int*   batch = (const int*)d_in[3];
  const float* aemb  = (const float*)d_in[4];
  const float* bemb  = (const float*)d_in[5];
  const float* vne   = (const float*)d_in[6];
  const float* cW1   = (const float*)d_in[7];
  const float* cb1   = (const float*)d_in[8];
  const float* cg1   = (const float*)d_in[9];
  const float* cbb1  = (const float*)d_in[10];
  const float* cW2   = (const float*)d_in[11];
  const float* cb2   = (const float*)d_in[12];
  const float* ng    = (const float*)d_in[13];
  const float* nb    = (const float*)d_in[14];
  const float* vW1   = (const float*)d_in[15];
  const float* vb1   = (const float*)d_in[16];
  const float* vg1   = (const float*)d_in[17];
  const float* vbb1  = (const float*)d_in[18];
  const float* vW2   = (const float*)d_in[19];
  const float* vb2   = (const float*)d_in[20];
  const float* vg2   = (const float*)d_in[21];
  const float* vbb2  = (const float*)d_in[22];
  float* out = (float*)d_out;

  const int nsb = (dgN + 255) / 256;

  const size_t fixed =
      dg35_al(dgG*dgC*4)*4 +
      dg35_al(8*2*dgC2*4) + dg35_al(2*dgC2*4) +
      dg35_al(8*2*dgC*4) +
      dg35_al(4*dgC*4) +
      dg35_al(2*dgC*4)*3 +
      dg35_al(dgN*4)*2 + dg35_al((dgN+1)*4) +
      dg35_al((dgG+1)*4) +
      dg35_al((size_t)dgE*4) +
      dg35_al(7*256*128*2)*4 +
      dg35_al(512*dgC*4) +
      dg35_al(256*4)*2;
  int af = 0;
  size_t esz = 2;
  {
    size_t bigf = dg35_al((size_t)dgN*dgC*4)*2 + dg35_al((size_t)dgN*dgC2*4);
    if (bigf + fixed <= ws_size){ af = 1; esz = 4; }
  }

  char* base = (char*)d_ws;
  size_t o = 0;
  void* h  = (void*)(base + o); o += dg35_al((size_t)dgN*dgC*esz);
  void* hh = (void*)(base + o); o += dg35_al((size_t)dgN*dgC*esz);
  void* zb = (void*)(base + o); o += dg35_al((size_t)dgN*dgC2*esz);
  float* vn   = (float*)(base + o); o += dg35_al(dgG*dgC*4);
  float* vt   = (float*)(base + o); o += dg35_al(dgG*dgC*4);
  float* zv1  = (float*)(base + o); o += dg35_al(dgG*dgC*4);
  float* zv2  = (float*)(base + o); o += dg35_al(dgG*dgC*4);
  float* st1  = (float*)(base + o); o += dg35_al(8*2*dgC2*4);
  float* ab1  = (float*)(base + o); o += dg35_al(2*dgC2*4);
  float* stH  = (float*)(base + o); o += dg35_al(8*2*dgC*4);
  float* stVV = (float*)(base + o); o += dg35_al(4*dgC*4);
  float* abh  = (float*)(base + o); o += dg35_al(2*dgC*4);
  float* abv1 = (float*)(base + o); o += dg35_al(2*dgC*4);
  float* abv2 = (float*)(base + o); o += dg35_al(2*dgC*4);
  int* deg = (int*)(base + o); o += dg35_al(dgN*4);
  int* cur = (int*)(base + o); o += dg35_al(dgN*4);
  int* off = (int*)(base + o); o += dg35_al((dgN+1)*4);
  int* gs  = (int*)(base + o); o += dg35_al((dgG+1)*4);
  dg35_u32* packed = (dg35_u32*)(base + o); o += dg35_al((size_t)dgE*4);
  short* Wt1h = (short*)(base + o); o += dg35_al(7*256*128*2);
  short* Wt1l = (short*)(base + o); o += dg35_al(7*256*128*2);
  short* Wt2h = (short*)(base + o); o += dg35_al(7*256*128*2);
  short* Wt2l = (short*)(base + o); o += dg35_al(7*256*128*2);
  float* ecomb = (float*)(base + o); o += dg35_al(512*dgC*4);
  int* bsum = (int*)(base + o); o += dg35_al(256*4);
  int* boff = (int*)(base + o); o += dg35_al(256*4);

  if (o > ws_size){
    hipMemsetAsync(d_out, 0x7F, (size_t)out_size*4, stream);
    return;
  }
  float* stV1 = stVV;
  float* stV2 = stVV + 2*dgC;
  void* h2 = zb;
  void* z  = zb;

  // ---- per-call setup ----
  hipMemsetAsync(deg, 0, sizeof(int)*dgN, stream);
  dg35_count  <<<(dgE+255)/256, 256, 0, stream>>>(eidx + dgE, deg, dgE);
  dg35_s1     <<<nsb, 256, 0, stream>>>(deg, bsum, dgN);
  dg35_s2     <<<1, 256, 0, stream>>>(bsum, boff, nsb);
  dg35_s3     <<<nsb, 256, 0, stream>>>(deg, boff, off, cur, dgN);
  dg35_scatter<<<(dgE+255)/256, 256, 0, stream>>>(eidx, eattr, cur, packed, dgE);
  dg35_gstart <<<(dgG+256)/256, 256, 0, stream>>>(batch, gs, dgN, dgG);
  dg35_atom   <<<dgN, dgC, 0, stream>>>(x, aemb, vne, h, af);
  dg35_vninit <<<(dgG*dgC)/256, 256, 0, stream>>>(vne, vn);
  dg35_wconv  <<<1792, 256, 0, stream>>>(cW1, cW2, Wt1h, Wt1l, Wt2h, Wt2l);
  dg35_ecomb  <<<512, 128, 0, stream>>>(bemb, ecomb);

  if (af){
    const int grb = (dgN + 63) / 64;   // 782 row-blocks (BM=64)
    for (int l = 0; l < 7; ++l){
      const float* hin = (const float*)h;
      hipMemsetAsync(st1, 0, 8*2*dgC2*sizeof(float), stream);
      if (l > 0){
        dg35_fin<<<1, 256, 0, stream>>>(stH, ng + (l-1)*dgC, nb + (l-1)*dgC,
                                        abh, 1.f/dgN, dgC, 8);
        hipMemsetAsync(stVV, 0, 4*dgC*sizeof(float), stream);
        dg35_h24<<<(dgN*dgC/4)/256, 256, 0, stream>>>((const float*)h, abh, (float*)h2);
        dg35_vt4<<<dgG, 128, 0, stream>>>((const float*)h2, vn, gs, vt);
        dg35_gemm_v<<<dim3(16,2), 256, 0, stream>>>(vt, vW1 + (l-1)*dgC*dgC,
                                                    vb1 + (l-1)*dgC, (const float*)0,
                                                    zv1, dgG, dgC, dgC, 0);
        dg35_cs4<<<64, 256, 0, stream>>>(zv1, stV1, dgG, dgC);
        dg35_fin<<<1, 256, 0, stream>>>(stV1, vg1 + (l-1)*dgC, vbb1 + (l-1)*dgC,
                                        abv1, 1.f/dgG, dgC, 1);
        dg35_gemm_v<<<dim3(16,2), 256, 0, stream>>>(zv1, vW2 + (l-1)*dgC*dgC,
                                                    vb2 + (l-1)*dgC, abv1,
                                                    zv2, dgG, dgC, dgC, 1);
        dg35_cs4<<<64, 256, 0, stream>>>(zv2, stV2, dgG, dgC);
        dg35_fin<<<1, 256, 0, stream>>>(stV2, vg2 + (l-1)*dgC, vbb2 + (l-1)*dgC,
                                        abv2, 1.f/dgG, dgC, 1);
        dg35_vnfin<<<(dgG*dgC)/256, 256, 0, stream>>>(zv2, abv2, vn);
        dg35_addvn4<<<(dgN*dgC/4)/256, 256, 0, stream>>>((float*)h2, vn, batch);
        hin = (const float*)h2;
      }
      dg35_gb2<<<(dgN+3)/4, 256, 0, stream>>>(hin, packed, off, ecomb, (float*)hh);
      dg35_gemmx<<<dim3(4, grb), 256, 0, stream>>>((const float*)hh,
                                                   Wt1h + l*32768, Wt1l + l*32768,
                                                   cb1 + l*dgC2, (const float*)0,
                                                   (const float*)0, (float*)z, st1,
                                                   dgN, dgC, dgC2, 0, 0);
      dg35_fin<<<1, 256, 0, stream>>>(st1, cg1 + l*dgC2, cbb1 + l*dgC2,
                                      ab1, 1.f/dgN, dgC2, 8);
      hipMemsetAsync(stH, 0, 8*2*dgC*sizeof(float), stream);
      dg35_gemmx<<<dim3(2, grb), 256, 0, stream>>>((const float*)z,
                                                   Wt2h + l*32768, Wt2l + l*32768,
                                                   cb2 + l*dgC, ab1,
                                                   (l==0) ? (const float*)0 : (const float*)h,
                                                   (float*)h, stH,
                                                   dgN, dgC2, dgC, 1, (l==0)?0:1);
    }
    dg35_fin<<<1, 256, 0, stream>>>(stH, ng + 6*dgC, nb + 6*dgC, abh, 1.f/dgN, dgC, 8);
    dg35_out4<<<dgG, 128, 0, stream>>>((const float*)h, abh, gs, out);
  } else {
    // tier-B fallback (bf16 storage, VALU GEMM)
    const int gx = (dgN + 63) / 64;
    for (int l = 0; l < 7; ++l){
      dg35_zero<<<1, 512, 0, stream>>>(st1, stH, stV1, stV2);
      const void* hin = h;
      if (l > 0){
        dg35_colstats<<<128, 256, 0, stream>>>(h, stH, dgN, dgC, af);
        dg35_fin<<<1, 256, 0, stream>>>(stH, ng + (l-1)*dgC, nb + (l-1)*dgC,
                                        abh, 1.f/dgN, dgC, 1);
        dg35_h2<<<(dgN*dgC)/256, 256, 0, stream>>>(h, abh, h2, af);
        dg35_vt<<<dgG, dgC, 0, stream>>>(h2, vn, gs, vt, af);
        dg35_gemm_v<<<dim3(16,2), 256, 0, stream>>>(vt, vW1 + (l-1)*dgC*dgC,
                                                    vb1 + (l-1)*dgC, (const float*)0,
                                                    zv1, dgG, dgC, dgC, 0);
        dg35_cs4<<<64, 256, 0, stream>>>(zv1, stV1, dgG, dgC);
        dg35_fin<<<1, 256, 0, stream>>>(stV1, vg1 + (l-1)*dgC, vbb1 + (l-1)*dgC,
                                        abv1, 1.f/dgG, dgC, 1);
        dg35_gemm_v<<<dim3(16,2), 256, 0, stream>>>(zv1, vW2 + (l-1)*dgC*dgC,
                                                    vb2 + (l-1)*dgC, abv1,
                                                    zv2, dgG, dgC, dgC, 1);
        dg35_cs4<<<64, 256, 0, stream>>>(zv2, stV2, dgG, dgC);
        dg35_fin<<<1, 256, 0, stream>>>(stV2, vg2 + (l-1)*dgC, vbb2 + (l-1)*dgC,
                                        abv2, 1.f/dgG, dgC, 1);
        dg35_vnfin<<<(dgG*dgC)/256, 256, 0, stream>>>(zv2, abv2, vn);
        dg35_addvn<<<dgN, dgC, 0, stream>>>(h2, vn, batch, af);
        hin = h2;
      }
      dg35_gb<<<dgN, dgC, 0, stream>>>(hin, packed, off, bemb, hh, af);
      dg35_gemm_h<<<dim3(gx,4), 256, 0, stream>>>(hh, cW1 + l*dgC*dgC2,
                                                  cb1 + l*dgC2, (const float*)0,
                                                  (const void*)0, z,
                                                  dgN, dgC, dgC2, 0, 0, af);
      dg35_colstats<<<128, 256, 0, stream>>>(z, st1, dgN, dgC2, af);
      dg35_fin<<<1, 256, 0, stream>>>(st1, cg1 + l*dgC2, cbb1 + l*dgC2,
                                      ab1, 1.f/dgN, dgC2, 1);
      dg35_gemm_h<<<dim3(gx,2), 256, 0, stream>>>(z, cW2 + l*dgC2*dgC,
                                                  cb2 + l*dgC, ab1, h, h,
                                                  dgN, dgC2, dgC, 1, (l==0)?0:1, af);
    }
    hipMemsetAsync(stH, 0, sizeof(float)*2*dgC, stream);
    dg35_colstats<<<128, 256, 0, stream>>>(h, stH, dgN, dgC, af);
    dg35_fin<<<1, 256, 0, stream>>>(stH, ng + 6*dgC, nb + 6*dgC, abh, 1.f/dgN, dgC, 1);
    dg35_out<<<dgG, dgC, 0, stream>>>(h, abh, gs, out, af);
  }
}

// Round 15
// 1368.430 us; speedup vs baseline: 1.1547x; 1.0297x over previous
//
#include <hip/hip_runtime.h>

typedef unsigned short dg35_u16;
typedef unsigned int   dg35_u32;

constexpr int dgN  = 50000;
constexpr int dgE  = 400000;
constexpr int dgG  = 1024;
constexpr int dgC  = 128;
constexpr int dgC2 = 256;

typedef __attribute__((ext_vector_type(8))) short dg35_s8v;   // 8 bf16 (4 VGPR)
typedef __attribute__((ext_vector_type(4))) float dg35_f4v;   // MFMA acc

__device__ __forceinline__ float dg35_bf2f(dg35_u16 u){
  return __uint_as_float(((dg35_u32)u) << 16);
}
__device__ __forceinline__ dg35_u16 dg35_f2bf(float f){
  dg35_u32 u = __float_as_uint(f);
  u += 0x7FFFu + ((u >> 16) & 1u);
  return (dg35_u16)(u >> 16);
}
__device__ __forceinline__ float dg35_ldx(const void* p, size_t i, int af){
  return af ? ((const float*)p)[i] : dg35_bf2f(((const dg35_u16*)p)[i]);
}
__device__ __forceinline__ void dg35_stx(void* p, size_t i, int af, float v){
  if (af) ((float*)p)[i] = v; else ((dg35_u16*)p)[i] = dg35_f2bf(v);
}

// Symbol from the harness template; kept but never launched.
__global__ void DeeperGCN_35820027248884_kernel(){}

// ---------------- CSR build ----------------
__global__ void dg35_count(const int* __restrict__ dst, int* __restrict__ deg, int e){
  int j = blockIdx.x*256 + threadIdx.x;
  if (j < e) atomicAdd(&deg[dst[j]], 1);
}

__global__ void dg35_s1(const int* __restrict__ deg, int* __restrict__ bsum, int n){
  __shared__ int sm[256];
  int t = threadIdx.x, b = blockIdx.x;
  int idx = b*256 + t;
  sm[t] = (idx < n) ? deg[idx] : 0;
  __syncthreads();
  for (int s = 128; s > 0; s >>= 1){
    if (t < s) sm[t] += sm[t+s];
    __syncthreads();
  }
  if (t == 0) bsum[b] = sm[0];
}

__global__ void dg35_s2(const int* __restrict__ bsum, int* __restrict__ boff, int nb){
  __shared__ int sm[256];
  int t = threadIdx.x;
  int v = (t < nb) ? bsum[t] : 0;
  sm[t] = v;
  __syncthreads();
  for (int s = 1; s < 256; s <<= 1){
    int u = (t >= s) ? sm[t-s] : 0;
    __syncthreads();
    sm[t] += u;
    __syncthreads();
  }
  if (t < nb) boff[t] = sm[t] - v;
}

__global__ void dg35_s3(const int* __restrict__ deg, const int* __restrict__ boff,
                        int* __restrict__ off, int* __restrict__ cur, int n){
  __shared__ int sm[256];
  int t = threadIdx.x, b = blockIdx.x;
  int idx = b*256 + t;
  int v = (idx < n) ? deg[idx] : 0;
  sm[t] = v;
  __syncthreads();
  for (int s = 1; s < 256; s <<= 1){
    int u = (t >= s) ? sm[t-s] : 0;
    __syncthreads();
    sm[t] += u;
    __syncthreads();
  }
  if (idx < n){
    int e = boff[b] + sm[t] - v;
    off[idx] = e; cur[idx] = e;
  }
  if (idx == 0) off[n] = dgE;
}

__global__ void dg35_scatter(const int* __restrict__ ei, const int* __restrict__ ea,
                             int* __restrict__ cur, dg35_u32* __restrict__ packed, int e){
  int j = blockIdx.x*256 + threadIdx.x;
  if (j >= e) return;
  int s = ei[j], d = ei[e + j];
  dg35_u32 a0 = (dg35_u32)ea[3*j], a1 = (dg35_u32)ea[3*j+1], a2 = (dg35_u32)ea[3*j+2];
  int pos = atomicAdd(&cur[d], 1);
  packed[pos] = (dg35_u32)s | (a0<<17) | (a1<<20) | (a2<<23);
}

__global__ void dg35_gstart(const int* __restrict__ batch, int* __restrict__ gs, int n, int g){
  int i = blockIdx.x*256 + threadIdx.x;
  if (i > g) return;
  if (i == g){ gs[i] = n; return; }
  int lo = 0, hi = n;
  while (lo < hi){ int mid = (lo+hi)>>1; if (batch[mid] < i) lo = mid+1; else hi = mid; }
  gs[i] = lo;
}

// ---------------- encoders / weight prep ----------------
__global__ __launch_bounds__(128)
void dg35_atom(const int* __restrict__ x, const float* __restrict__ aemb,
               const float* __restrict__ vne, void* __restrict__ h, int af){
  int i = blockIdx.x, c = threadIdx.x;
  float acc = vne[c];
  #pragma unroll
  for (int f = 0; f < 9; ++f){
    int idx = x[i*9 + f];
    acc += aemb[(f*128 + idx)*dgC + c];
  }
  dg35_stx(h, (size_t)i*dgC + c, af, acc);
}

__global__ void dg35_vninit(const float* __restrict__ vne, float* __restrict__ vn){
  int i = blockIdx.x*256 + threadIdx.x;
  if (i < dgG*dgC) vn[i] = vne[i & (dgC-1)];
}

// combo table: ecomb[c9][c] = bemb[a0][c] + bemb[8+a1][c] + bemb[16+a2][c]
__global__ __launch_bounds__(128)
void dg35_ecomb(const float* __restrict__ bemb, float* __restrict__ ecomb){
  int c9 = blockIdx.x, t = threadIdx.x;
  int a0 = c9 & 7, a1 = (c9 >> 3) & 7, a2 = (c9 >> 6) & 7;
  ecomb[c9*dgC + t] = bemb[a0*dgC + t] + bemb[(8+a1)*dgC + t] + bemb[(16+a2)*dgC + t];
}

// transpose+convert conv weights to SPLIT bf16 (hi+lo) in [l][n][k] layout
__global__ void dg35_wconv(const float* __restrict__ W1, const float* __restrict__ W2,
                           short* __restrict__ Wt1h, short* __restrict__ Wt1l,
                           short* __restrict__ Wt2h, short* __restrict__ Wt2l){
  int i = blockIdx.x*256 + threadIdx.x;
  constexpr int per = 7*256*128;
  float w;
  short* ph; short* pl; int oidx;
  if (i < per){
    int l = i >> 15;
    int rem = i & 32767;
    int n = rem >> 7;
    int k = rem & 127;
    w = W1[l*32768 + k*256 + n];
    ph = Wt1h; pl = Wt1l; oidx = i;
  } else {
    int j = i - per;
    int l = j >> 15;
    int rem = j & 32767;
    int n = rem >> 8;
    int k = rem & 255;
    w = W2[l*32768 + k*128 + n];
    ph = Wt2h; pl = Wt2l; oidx = j;
  }
  dg35_u16 hi = dg35_f2bf(w);
  float lo = w - dg35_bf2f(hi);
  ph[oidx] = (short)hi;
  pl[oidx] = (short)dg35_f2bf(lo);
}

__global__ void dg35_zero(float* a, float* b, float* c_, float* d){
  int t = threadIdx.x;
  if (t < 512) a[t] = 0.f;
  if (t < 256){ b[t]=0.f; c_[t]=0.f; d[t]=0.f; }
}

// ------------- GENConv softmax aggr: exp-direct (shift-8), 2 ch/lane, 2 edge streams ----
__global__ __launch_bounds__(256)
void dg35_gb2(const float* __restrict__ hin, const dg35_u32* __restrict__ packed,
              const int* __restrict__ off, const float* __restrict__ ecomb,
              float* __restrict__ hh){
  int i = blockIdx.x*4 + (threadIdx.x >> 6);
  if (i >= dgN) return;
  int c = (threadIdx.x & 63) * 2;
  int b0 = off[i], b1 = off[i+1];
  float2 self = *reinterpret_cast<const float2*>(hin + (size_t)i*dgC + c);
  float sA0=0.f, wA0=0.f, sA1=0.f, wA1=0.f;
  float sB0=0.f, wB0=0.f, sB1=0.f, wB1=0.f;
  int p = b0;
  for (; p + 1 < b1; p += 2){
    dg35_u32 pkA = packed[p], pkB = packed[p+1];
    int srcA = (int)(pkA & 0x1FFFFu), srcB = (int)(pkB & 0x1FFFFu);
    float2 hA = *reinterpret_cast<const float2*>(hin + (size_t)srcA*dgC + c);
    float2 hB = *reinterpret_cast<const float2*>(hin + (size_t)srcB*dgC + c);
    float2 eA = *reinterpret_cast<const float2*>(ecomb + (size_t)(pkA>>17)*dgC + c);
    float2 eB = *reinterpret_cast<const float2*>(ecomb + (size_t)(pkB>>17)*dgC + c);
    float msgA0 = fmaxf(hA.x + eA.x, 0.f) + 1e-7f;
    float msgA1 = fmaxf(hA.y + eA.y, 0.f) + 1e-7f;
    float msgB0 = fmaxf(hB.x + eB.x, 0.f) + 1e-7f;
    float msgB1 = fmaxf(hB.y + eB.y, 0.f) + 1e-7f;
    float tA0 = __expf(msgA0 - 8.f), tA1 = __expf(msgA1 - 8.f);
    float tB0 = __expf(msgB0 - 8.f), tB1 = __expf(msgB1 - 8.f);
    sA0 += tA0; wA0 = fmaf(msgA0, tA0, wA0);
    sA1 += tA1; wA1 = fmaf(msgA1, tA1, wA1);
    sB0 += tB0; wB0 = fmaf(msgB0, tB0, wB0);
    sB1 += tB1; wB1 = fmaf(msgB1, tB1, wB1);
  }
  if (p < b1){
    dg35_u32 pkA = packed[p];
    int srcA = (int)(pkA & 0x1FFFFu);
    float2 hA = *reinterpret_cast<const float2*>(hin + (size_t)srcA*dgC + c);
    float2 eA = *reinterpret_cast<const float2*>(ecomb + (size_t)(pkA>>17)*dgC + c);
    float msg0 = fmaxf(hA.x + eA.x, 0.f) + 1e-7f;
    float msg1 = fmaxf(hA.y + eA.y, 0.f) + 1e-7f;
    float t0 = __expf(msg0 - 8.f), t1 = __expf(msg1 - 8.f);
    sA0 += t0; wA0 = fmaf(msg0, t0, wA0);
    sA1 += t1; wA1 = fmaf(msg1, t1, wA1);
  }
  float s0 = sA0 + sB0, w0 = wA0 + wB0;
  float s1 = sA1 + sB1, w1 = wA1 + wB1;
  float2 o;
  o.x = self.x + ((b1 > b0) ? (w0 / (s0 + 1e-16f)) : 0.f);
  o.y = self.y + ((b1 > b0) ? (w1 / (s1 + 1e-16f)) : 0.f);
  *reinterpret_cast<float2*>(hh + (size_t)i*dgC + c) = o;
}

// ---- split-bf16 MFMA GEMM, BM=64, A+B LDS-staged (swizzled), COALESCED staging,
//      prefetch, fused column stats (8-way replicated), XCD chunk swizzle ----
// Staging remap: consecutive lanes read consecutive 16B (one wave instr = 1KB contig).
// A: thread t, piece i in 0..3: row = i*16 + t/16, f32 cols (t&15)*4 .. +3.
// B: thread t, piece j in 0..1: row = j*32 + t/8, short slot t&7 (8 shorts = 16B).
__global__ __launch_bounds__(256)
void dg35_gemmx(const float* __restrict__ A, const short* __restrict__ Whi,
                const short* __restrict__ Wlo, const float* __restrict__ bias,
                const float* __restrict__ ab, const float* __restrict__ res,
                float* __restrict__ Cout, float* __restrict__ st,
                int M, int K, int NC, int trans, int addres){
  __shared__ short Ahi[64*64];   // 8 KB
  __shared__ short Alo[64*64];   // 8 KB
  __shared__ short Bhs[64*64];   // 8 KB
  __shared__ short Bls[64*64];   // 8 KB
  int tid = threadIdx.x;
  // bijective XCD chunk swizzle (m204)
  int nwg = gridDim.x * gridDim.y;
  int lin = blockIdx.y * gridDim.x + blockIdx.x;
  int q8 = nwg >> 3, r8 = nwg & 7;
  int xcd = lin & 7, pos = lin >> 3;
  int wg = (xcd < r8) ? (xcd*(q8+1) + pos) : (r8*(q8+1) + (xcd-r8)*q8 + pos);
  int bn = (wg % gridDim.x) * 64;
  int bm = (wg / gridDim.x) * 64;
  float* stc = st + (size_t)(wg & 7) * 2 * NC;
  int lane = tid & 63;
  int wv = tid >> 6;
  int l15 = lane & 15;
  int l4  = lane >> 4;
  dg35_f4v acc[4] = {};

  // coalesced staging coords
  int rA0  = tid >> 4;          // A base row (piece adds i*16)
  int colf = (tid & 15) * 4;    // f32 col within 64-wide tile
  int c8   = colf >> 3;         // pre-swizzle 16B-slot index
  int halfo = ((colf >> 2) & 1) * 4;  // short offset within slot
  int rB0 = tid >> 3;           // B base row (piece adds j*32)
  int sB  = tid & 7;            // B pre-swizzle slot

  float4 va[4];
  #pragma unroll
  for (int i = 0; i < 4; ++i){
    int row = bm + i*16 + rA0;
    va[i] = (row < M) ? *reinterpret_cast<const float4*>(A + (size_t)row*K + colf)
                      : make_float4(0.f,0.f,0.f,0.f);
  }

  for (int k0 = 0; k0 < K; k0 += 64){
    // issue B loads (coalesced; latency overlaps A conversion)
    uint4 bth[2], btl[2];
    #pragma unroll
    for (int j = 0; j < 2; ++j){
      int rowB = j*32 + rB0;
      size_t wo = (size_t)(bn + rowB)*K + k0 + sB*8;
      bth[j] = *reinterpret_cast<const uint4*>(Whi + wo);
      btl[j] = *reinterpret_cast<const uint4*>(Wlo + wo);
    }
    // BN coefficients for this thread's 4 columns (shared across pieces)
    float aK[4], bK[4];
    if (trans){
      #pragma unroll
      for (int e = 0; e < 4; ++e){
        aK[e] = ab[k0 + colf + e];
        bK[e] = ab[K + k0 + colf + e];
      }
    }
    // convert A pieces -> swizzled split-bf16 LDS (8B per piece per buffer)
    #pragma unroll
    for (int i = 0; i < 4; ++i){
      int rowA = i*16 + rA0;
      float xv[4] = {va[i].x, va[i].y, va[i].z, va[i].w};
      if (trans){
        #pragma unroll
        for (int e = 0; e < 4; ++e) xv[e] = fmaxf(xv[e]*aK[e] + bK[e], 0.f);
      }
      unsigned hp0, hp1, lp0, lp1;
      {
        dg35_u16 h0 = dg35_f2bf(xv[0]), h1 = dg35_f2bf(xv[1]);
        dg35_u16 l0 = dg35_f2bf(xv[0] - dg35_bf2f(h0));
        dg35_u16 l1 = dg35_f2bf(xv[1] - dg35_bf2f(h1));
        hp0 = (dg35_u32)h0 | ((dg35_u32)h1 << 16);
        lp0 = (dg35_u32)l0 | ((dg35_u32)l1 << 16);
      }
      {
        dg35_u16 h0 = dg35_f2bf(xv[2]), h1 = dg35_f2bf(xv[3]);
        dg35_u16 l0 = dg35_f2bf(xv[2] - dg35_bf2f(h0));
        dg35_u16 l1 = dg35_f2bf(xv[3] - dg35_bf2f(h1));
        hp1 = (dg35_u32)h0 | ((dg35_u32)h1 << 16);
        lp1 = (dg35_u32)l0 | ((dg35_u32)l1 << 16);
      }
      int off = rowA*64 + ((c8 ^ (rowA & 7)) << 3) + halfo;
      *reinterpret_cast<uint2*>(&Ahi[off]) = make_uint2(hp0, hp1);
      *reinterpret_cast<uint2*>(&Alo[off]) = make_uint2(lp0, lp1);
    }
    // write B to swizzled LDS (one full 16B slot per piece)
    #pragma unroll
    for (int j = 0; j < 2; ++j){
      int rowB = j*32 + rB0;
      int offB = rowB*64 + ((sB ^ (rowB & 7)) << 3);
      *reinterpret_cast<uint4*>(&Bhs[offB]) = bth[j];
      *reinterpret_cast<uint4*>(&Bls[offB]) = btl[j];
    }
    __syncthreads();
    // prefetch next A tile (overlaps MFMA; invalid rows stay zero from prologue)
    if (k0 + 64 < K){
      #pragma unroll
      for (int i = 0; i < 4; ++i){
        int row = bm + i*16 + rA0;
        if (row < M)
          va[i] = *reinterpret_cast<const float4*>(A + (size_t)row*K + k0 + 64 + colf);
      }
    }
    // MFMA over 2 K-steps of 32, A and B both from LDS (read side unchanged)
    #pragma unroll
    for (int ks = 0; ks < 2; ++ks){
      dg35_s8v bh[4], bl[4];
      #pragma unroll
      for (int nf = 0; nf < 4; ++nf){
        int n = nf*16 + l15;
        int slot = (ks*4 + l4) ^ (n & 7);
        bh[nf] = *reinterpret_cast<const dg35_s8v*>(&Bhs[n*64 + slot*8]);
        bl[nf] = *reinterpret_cast<const dg35_s8v*>(&Bls[n*64 + slot*8]);
      }
      int row = wv*16 + l15;
      int slotA = (ks*4 + l4) ^ (row & 7);
      dg35_s8v ah = *reinterpret_cast<const dg35_s8v*>(&Ahi[row*64 + slotA*8]);
      dg35_s8v al = *reinterpret_cast<const dg35_s8v*>(&Alo[row*64 + slotA*8]);
      #pragma unroll
      for (int nf = 0; nf < 4; ++nf){
        acc[nf] = __builtin_amdgcn_mfma_f32_16x16x32_bf16(ah, bh[nf], acc[nf], 0, 0, 0);
        acc[nf] = __builtin_amdgcn_mfma_f32_16x16x32_bf16(al, bh[nf], acc[nf], 0, 0, 0);
        acc[nf] = __builtin_amdgcn_mfma_f32_16x16x32_bf16(ah, bl[nf], acc[nf], 0, 0, 0);
      }
    }
    __syncthreads();
  }
  // epilogue: write + per-lane col partial stats
  float s[4] = {0.f,0.f,0.f,0.f}, q[4] = {0.f,0.f,0.f,0.f};
  #pragma unroll
  for (int e = 0; e < 4; ++e){
    int rr = bm + wv*16 + l4*4 + e;
    if (rr >= M) continue;
    #pragma unroll
    for (int nf = 0; nf < 4; ++nf){
      int cc = bn + nf*16 + l15;
      float v = acc[nf][e] + bias[cc];
      size_t idx = (size_t)rr*NC + cc;
      if (addres) v += res[idx];
      Cout[idx] = v;
      s[nf] += v; q[nf] += v*v;
    }
  }
  #pragma unroll
  for (int nf = 0; nf < 4; ++nf){
    s[nf] += __shfl_xor(s[nf], 16); s[nf] += __shfl_xor(s[nf], 32);
    q[nf] += __shfl_xor(q[nf], 16); q[nf] += __shfl_xor(q[nf], 32);
  }
  __syncthreads();
  float* red = (float*)Ahi;
  if (l4 == 0){
    #pragma unroll
    for (int nf = 0; nf < 4; ++nf){
      red[wv*128 + nf*16 + l15] = s[nf];
      red[wv*128 + 64 + nf*16 + l15] = q[nf];
    }
  }
  __syncthreads();
  if (tid < 64){
    float S = red[tid] + red[128+tid] + red[256+tid] + red[384+tid];
    float Q = red[64+tid] + red[192+tid] + red[320+tid] + red[448+tid];
    atomicAdd(&stc[bn + tid], S);
    atomicAdd(&stc[NC + bn + tid], Q);
  }
}

// -------- VALU GEMM (dual-precision) — tier-B fallback only --------
__global__ __launch_bounds__(256)
void dg35_gemm_h(const void* __restrict__ A, const float* __restrict__ W,
                 const float* __restrict__ bias, const float* __restrict__ ab,
                 const void* __restrict__ res, void* __restrict__ Cout,
                 int M, int K, int NC, int trans, int addres, int af){
  __shared__ float At[32][65];
  __shared__ float Bt[32][64];
  int bm = blockIdx.x * 64;
  int bn = blockIdx.y * 64;
  int tid = threadIdx.x;
  int tx = tid & 15, ty = tid >> 4;
  float acc[4][4];
  #pragma unroll
  for (int i2 = 0; i2 < 4; ++i2)
    #pragma unroll
    for (int j2 = 0; j2 < 4; ++j2) acc[i2][j2] = 0.f;

  for (int k0 = 0; k0 < K; k0 += 32){
    int r = tid >> 3;
    int kq = (tid & 7) * 4;
    #pragma unroll
    for (int half = 0; half < 2; ++half){
      int rr = r + half*32;
      int grow = bm + rr;
      float vv[4] = {0.f, 0.f, 0.f, 0.f};
      if (grow < M){
        if (af){
          float4 v4 = *reinterpret_cast<const float4*>((const float*)A + (size_t)grow*K + k0 + kq);
          vv[0] = v4.x; vv[1] = v4.y; vv[2] = v4.z; vv[3] = v4.w;
        } else {
          ushort4 v4 = *reinterpret_cast<const ushort4*>((const dg35_u16*)A + (size_t)grow*K + k0 + kq);
          vv[0] = dg35_bf2f(v4.x); vv[1] = dg35_bf2f(v4.y);
          vv[2] = dg35_bf2f(v4.z); vv[3] = dg35_bf2f(v4.w);
        }
      }
      #pragma unroll
      for (int i2 = 0; i2 < 4; ++i2){
        float xv = vv[i2];
        if (trans){
          int kk = k0 + kq + i2;
          xv = fmaxf(xv*ab[kk] + ab[K + kk], 0.f);
        }
        At[kq + i2][rr] = xv;
      }
    }
    {
      int kr = tid >> 3;
      int cq = (tid & 7) * 8;
      const float* wp = W + (size_t)(k0 + kr)*NC + bn + cq;
      #pragma unroll
      for (int i2 = 0; i2 < 8; ++i2) Bt[kr][cq + i2] = wp[i2];
    }
    __syncthreads();
    #pragma unroll
    for (int kk = 0; kk < 32; ++kk){
      float a4[4], b4[4];
      #pragma unroll
      for (int i2 = 0; i2 < 4; ++i2) a4[i2] = At[kk][ty*4 + i2];
      #pragma unroll
      for (int j2 = 0; j2 < 4; ++j2) b4[j2] = Bt[kk][tx*4 + j2];
      #pragma unroll
      for (int i2 = 0; i2 < 4; ++i2)
        #pragma unroll
        for (int j2 = 0; j2 < 4; ++j2)
          acc[i2][j2] += a4[i2]*b4[j2];
    }
    __syncthreads();
  }
  #pragma unroll
  for (int i2 = 0; i2 < 4; ++i2){
    int rr = bm + ty*4 + i2;
    if (rr >= M) continue;
    #pragma unroll
    for (int j2 = 0; j2 < 4; ++j2){
      int cc = bn + tx*4 + j2;
      float v = acc[i2][j2] + bias[cc];
      size_t idx = (size_t)rr*NC + cc;
      if (addres) v += dg35_ldx(res, idx, af);
      dg35_stx(Cout, idx, af, v);
    }
  }
}

// -------- GEMM, A f32, W f32, f32 out (virtual-node MLP, M=1024) --------
__global__ __launch_bounds__(256)
void dg35_gemm_v(const float* __restrict__ A, const float* __restrict__ W,
                 const float* __restrict__ bias, const float* __restrict__ ab,
                 float* __restrict__ Cout, int M, int K, int NC, int trans){
  __shared__ float At[32][65];
  __shared__ float Bt[32][64];
  int bm = blockIdx.x * 64;
  int bn = blockIdx.y * 64;
  int tid = threadIdx.x;
  int tx = tid & 15, ty = tid >> 4;
  float acc[4][4];
  #pragma unroll
  for (int i2 = 0; i2 < 4; ++i2)
    #pragma unroll
    for (int j2 = 0; j2 < 4; ++j2) acc[i2][j2] = 0.f;

  for (int k0 = 0; k0 < K; k0 += 32){
    int r = tid >> 3;
    int kq = (tid & 7) * 4;
    #pragma unroll
    for (int half = 0; half < 2; ++half){
      int rr = r + half*32;
      int grow = bm + rr;
      float vv[4] = {0.f, 0.f, 0.f, 0.f};
      if (grow < M){
        float4 v4 = *reinterpret_cast<const float4*>(A + (size_t)grow*K + k0 + kq);
        vv[0] = v4.x; vv[1] = v4.y; vv[2] = v4.z; vv[3] = v4.w;
      }
      #pragma unroll
      for (int i2 = 0; i2 < 4; ++i2){
        float xv = vv[i2];
        if (trans){
          int kk = k0 + kq + i2;
          xv = fmaxf(xv*ab[kk] + ab[K + kk], 0.f);
        }
        At[kq + i2][rr] = xv;
      }
    }
    {
      int kr = tid >> 3;
      int cq = (tid & 7) * 8;
      const float* wp = W + (size_t)(k0 + kr)*NC + bn + cq;
      #pragma unroll
      for (int i2 = 0; i2 < 8; ++i2) Bt[kr][cq + i2] = wp[i2];
    }
    __syncthreads();
    #pragma unroll
    for (int kk = 0; kk < 32; ++kk){
      float a4[4], b4[4];
      #pragma unroll
      for (int i2 = 0; i2 < 4; ++i2) a4[i2] = At[kk][ty*4 + i2];
      #pragma unroll
      for (int j2 = 0; j2 < 4; ++j2) b4[j2] = Bt[kk][tx*4 + j2];
      #pragma unroll
      for (int i2 = 0; i2 < 4; ++i2)
        #pragma unroll
        for (int j2 = 0; j2 < 4; ++j2)
          acc[i2][j2] += a4[i2]*b4[j2];
    }
    __syncthreads();
  }
  #pragma unroll
  for (int i2 = 0; i2 < 4; ++i2){
    int rr = bm + ty*4 + i2;
    if (rr >= M) continue;
    #pragma unroll
    for (int j2 = 0; j2 < 4; ++j2){
      int cc = bn + tx*4 + j2;
      Cout[(size_t)rr*NC + cc] = acc[i2][j2] + bias[cc];
    }
  }
}

// ---------------- BN statistics (small f32 buffers: zv1/zv2) ----------------
__global__ __launch_bounds__(256)
void dg35_cs4(const float* __restrict__ Z, float* __restrict__ st, int n, int ncols){
  int t = threadIdx.x;
  int lpr = ncols >> 2;
  int rl = t / lpr;
  int rpb = 256 / lpr;
  int cq = (t - rl*lpr) * 4;
  float4 s = make_float4(0.f,0.f,0.f,0.f);
  float4 q = make_float4(0.f,0.f,0.f,0.f);
  for (int rr = blockIdx.x*rpb + rl; rr < n; rr += gridDim.x*rpb){
    float4 v = *reinterpret_cast<const float4*>(Z + (size_t)rr*ncols + cq);
    s.x += v.x; s.y += v.y; s.z += v.z; s.w += v.w;
    q.x += v.x*v.x; q.y += v.y*v.y; q.z += v.z*v.z; q.w += v.w*v.w;
  }
  __shared__ float sm[256*8];
  float* my = &sm[t*8];
  my[0]=s.x; my[1]=s.y; my[2]=s.z; my[3]=s.w;
  my[4]=q.x; my[5]=q.y; my[6]=q.z; my[7]=q.w;
  __syncthreads();
  if (rl == 0){
    float a[8];
    #pragma unroll
    for (int d = 0; d < 8; ++d) a[d] = my[d];
    for (int j = 1; j < rpb; ++j){
      const float* o2 = &sm[(t + j*lpr)*8];
      #pragma unroll
      for (int d = 0; d < 8; ++d) a[d] += o2[d];
    }
    #pragma unroll
    for (int d = 0; d < 4; ++d) atomicAdd(&st[cq + d], a[d]);
    #pragma unroll
    for (int d = 0; d < 4; ++d) atomicAdd(&st[ncols + cq + d], a[4 + d]);
  }
}

// tier-B fallback colstats
__global__ void dg35_colstats(const void* __restrict__ Z, float* __restrict__ st,
                              int n, int ncols, int af){
  int tid = threadIdx.x;
  int c = tid & (ncols - 1);
  int rl = tid / ncols;
  int rpb = 256 / ncols;
  float s = 0.f, q = 0.f;
  for (int rr = blockIdx.x*rpb + rl; rr < n; rr += gridDim.x*rpb){
    float v = dg35_ldx(Z, (size_t)rr*ncols + c, af);
    s += v; q += v*v;
  }
  atomicAdd(&st[c], s);
  atomicAdd(&st[ncols + c], q);
}

// finalize BN affine from (possibly replicated) stats
__global__ void dg35_fin(const float* __restrict__ st, const float* __restrict__ g,
                         const float* __restrict__ b, float* __restrict__ ab,
                         float inv_n, int ncols, int ncopy){
  int c = threadIdx.x + blockIdx.x*256;
  if (c >= ncols) return;
  float m = 0.f, q = 0.f;
  for (int k = 0; k < ncopy; ++k){
    m += st[(size_t)k*2*ncols + c];
    q += st[(size_t)k*2*ncols + ncols + c];
  }
  m *= inv_n;
  float var = q*inv_n - m*m;
  float rstd = rsqrtf(var + 1e-5f);
  float a = g[c]*rstd;
  ab[c] = a;
  ab[ncols + c] = b[c] - m*a;
}

// ---------------- elementwise / segment ops ----------------
__global__ void dg35_h24(const float* __restrict__ h, const float* __restrict__ ab,
                         float* __restrict__ h2){
  int i = blockIdx.x*256 + threadIdx.x;
  int c = (i & 31) * 4;
  float4 v = reinterpret_cast<const float4*>(h)[i];
  v.x = fmaxf(v.x*ab[c+0] + ab[dgC+c+0], 0.f);
  v.y = fmaxf(v.y*ab[c+1] + ab[dgC+c+1], 0.f);
  v.z = fmaxf(v.z*ab[c+2] + ab[dgC+c+2], 0.f);
  v.w = fmaxf(v.w*ab[c+3] + ab[dgC+c+3], 0.f);
  reinterpret_cast<float4*>(h2)[i] = v;
}

__global__ void dg35_h2(const void* __restrict__ h, const float* __restrict__ ab,
                        void* __restrict__ h2, int af){
  int i = blockIdx.x*256 + threadIdx.x;
  int c = i & (dgC-1);
  dg35_stx(h2, i, af, fmaxf(dg35_ldx(h, i, af)*ab[c] + ab[dgC + c], 0.f));
}

__global__ __launch_bounds__(128)
void dg35_vt4(const float* __restrict__ h2, const float* __restrict__ vn,
              const int* __restrict__ gs, float* __restrict__ vt){
  int g = blockIdx.x, t = threadIdx.x;
  int rl = t >> 5, cl = t & 31;
  int cq = cl*4;
  int r0 = gs[g], r1 = gs[g+1];
  float4 s = make_float4(0.f,0.f,0.f,0.f);
  for (int rr = r0 + rl; rr < r1; rr += 4){
    float4 v = *reinterpret_cast<const float4*>(h2 + (size_t)rr*dgC + cq);
    s.x += v.x; s.y += v.y; s.z += v.z; s.w += v.w;
  }
  __shared__ float4 sm[128];
  sm[t] = s;
  __syncthreads();
  if (rl == 0){
    float4 a = sm[cl], b = sm[32+cl], c4 = sm[64+cl], d = sm[96+cl];
    float4 vb = *reinterpret_cast<const float4*>(vn + (size_t)g*dgC + cq);
    float4 o;
    o.x = a.x+b.x+c4.x+d.x + vb.x;
    o.y = a.y+b.y+c4.y+d.y + vb.y;
    o.z = a.z+b.z+c4.z+d.z + vb.z;
    o.w = a.w+b.w+c4.w+d.w + vb.w;
    *reinterpret_cast<float4*>(vt + (size_t)g*dgC + cq) = o;
  }
}

__global__ __launch_bounds__(128)
void dg35_vt(const void* __restrict__ h2, const float* __restrict__ vn,
             const int* __restrict__ gs, float* __restrict__ vt, int af){
  int g = blockIdx.x, c = threadIdx.x;
  float s = 0.f;
  int r0 = gs[g], r1 = gs[g+1];
  for (int rr = r0; rr < r1; ++rr) s += dg35_ldx(h2, (size_t)rr*dgC + c, af);
  vt[g*dgC + c] = s + vn[g*dgC + c];
}

__global__ void dg35_vnfin(const float* __restrict__ z2, const float* __restrict__ ab,
                           float* __restrict__ vn){
  int i = blockIdx.x*256 + threadIdx.x;
  int c = i & (dgC-1);
  vn[i] = fmaxf(z2[i]*ab[c] + ab[dgC + c], 0.f);
}

__global__ void dg35_addvn4(float* __restrict__ h2, const float* __restrict__ vn,
                            const int* __restrict__ batch){
  int i = blockIdx.x*256 + threadIdx.x;
  int row = i >> 5;
  int cl = i & 31;
  float4 v = reinterpret_cast<float4*>(h2)[i];
  float4 a = reinterpret_cast<const float4*>(vn)[batch[row]*32 + cl];
  v.x += a.x; v.y += a.y; v.z += a.z; v.w += a.w;
  reinterpret_cast<float4*>(h2)[i] = v;
}

__global__ __launch_bounds__(128)
void dg35_addvn(void* __restrict__ h2, const float* __restrict__ vn,
                const int* __restrict__ batch, int af){
  int i = blockIdx.x, c = threadIdx.x;
  size_t idx = (size_t)i*dgC + c;
  dg35_stx(h2, idx, af, dg35_ldx(h2, idx, af) + vn[batch[i]*dgC + c]);
}

__global__ __launch_bounds__(128)
void dg35_out4(const float* __restrict__ h, const float* __restrict__ ab,
               const int* __restrict__ gs, float* __restrict__ out){
  int g = blockIdx.x, t = threadIdx.x;
  int rl = t >> 5, cl = t & 31;
  int cq = cl*4;
  int r0 = gs[g], r1 = gs[g+1];
  float4 s = make_float4(0.f,0.f,0.f,0.f);
  for (int rr = r0 + rl; rr < r1; rr += 4){
    float4 v = *reinterpret_cast<const float4*>(h + (size_t)rr*dgC + cq);
    s.x += v.x; s.y += v.y; s.z += v.z; s.w += v.w;
  }
  __shared__ float4 sm[128];
  sm[t] = s;
  __syncthreads();
  if (rl == 0){
    float4 a4 = sm[cl], b4 = sm[32+cl], c4 = sm[64+cl], d4 = sm[96+cl];
    float cnt = (float)(r1 - r0);
    float4 o;
    float S;
    S = a4.x+b4.x+c4.x+d4.x; o.x = ab[cq+0]*S + ab[dgC+cq+0]*cnt;
    S = a4.y+b4.y+c4.y+d4.y; o.y = ab[cq+1]*S + ab[dgC+cq+1]*cnt;
    S = a4.z+b4.z+c4.z+d4.z; o.z = ab[cq+2]*S + ab[dgC+cq+2]*cnt;
    S = a4.w+b4.w+c4.w+d4.w; o.w = ab[cq+3]*S + ab[dgC+cq+3]*cnt;
    *reinterpret_cast<float4*>(out + (size_t)g*dgC + cq) = o;
  }
}

// tier-B fallback pieces
__global__ __launch_bounds__(128)
void dg35_gb(const void* __restrict__ hin, const dg35_u32* __restrict__ packed,
             const int* __restrict__ off, const float* __restrict__ bemb,
             void* __restrict__ hh, int af){
  int i = blockIdx.x, c = threadIdx.x;
  int b0 = off[i], b1 = off[i+1];
  float m = -3.0e38f, s = 0.f, w = 0.f;
  for (int p = b0; p < b1; ++p){
    dg35_u32 pk = packed[p];
    int src = (int)(pk & 0x1FFFFu);
    float e = bemb[((pk>>17)&7)*dgC + c] + bemb[(8+((pk>>20)&7))*dgC + c]
            + bemb[(16+((pk>>23)&7))*dgC + c];
    float msg = fmaxf(dg35_ldx(hin, (size_t)src*dgC + c, af) + e, 0.f) + 1e-7f;
    float mn = fmaxf(m, msg);
    float sc = __expf(m - mn), t2 = __expf(msg - mn);
    s = s*sc + t2; w = w*sc + msg*t2; m = mn;
  }
  float agg = (b1 > b0) ? (w / (s + 1e-16f)) : 0.f;
  float self = dg35_ldx(hin, (size_t)i*dgC + c, af);
  dg35_stx(hh, (size_t)i*dgC + c, af, self + agg);
}

__global__ __launch_bounds__(128)
void dg35_out(const void* __restrict__ h, const float* __restrict__ ab,
              const int* __restrict__ gs, float* __restrict__ out, int af){
  int g = blockIdx.x, c = threadIdx.x;
  float a = ab[c], b = ab[dgC + c];
  float s = 0.f;
  int r0 = gs[g], r1 = gs[g+1];
  for (int rr = r0; rr < r1; ++rr) s += dg35_ldx(h, (size_t)rr*dgC + c, af)*a + b;
  out[g*dgC + c] = s;
}

static inline size_t dg35_al(size_t x){ return (x + 255) & ~(size_t)255; }

extern "C" void kernel_launch(void* const* d_in, const int* in_sizes, int n_in,
                              void* d_out, int out_size, void* d_ws, size_t ws_size,
                              hipStream_t stream)
{
  const int*   x     = (const int*)d_in[0];
  const int*   eattr = (const int*)d_in[1];
  const int*   eidx  = (const int*)d_in[2];
  const int*   batch = (const int*)d_in[3];
  const float* aemb  = (const float*)d_in[4];
  const float* bemb  = (const float*)d_in[5];
  const float* vne   = (const float*)d_in[6];
  const float* cW1   = (const float*)d_in[7];
  const float* cb1   = (const float*)d_in[8];
  const float* cg1   = (const float*)d_in[9];
  const float* cbb1  = (const float*)d_in[10];
  const float* cW2   = (const float*)d_in[11];
  const float* cb2   = (const float*)d_in[12];
  const float* ng    = (const float*)d_in[13];
  const float* nb    = (const float*)d_in[14];
  const float* vW1   = (const float*)d_in[15];
  const float* vb1   = (const float*)d_in[16];
  const float* vg1   = (const float*)d_in[17];
  const float* vbb1  = (const float*)d_in[18];
  const float* vW2   = (const float*)d_in[19];
  const float* vb2   = (const float*)d_in[20];
  const float* vg2   = (const float*)d_in[21];
  const float* vbb2  = (const float*)d_in[22];
  float* out = (float*)d_out;

  const int nsb = (dgN + 255) / 256;

  const size_t fixed =
      dg35_al(dgG*dgC*4)*4 +
      dg35_al(8*2*dgC2*4) + dg35_al(2*dgC2*4) +
      dg35_al(8*2*dgC*4) +
      dg35_al(4*dgC*4) +
      dg35_al(2*dgC*4)*3 +
      dg35_al(dgN*4)*2 + dg35_al((dgN+1)*4) +
      dg35_al((dgG+1)*4) +
      dg35_al((size_t)dgE*4) +
      dg35_al(7*256*128*2)*4 +
      dg35_al(512*dgC*4) +
      dg35_al(256*4)*2;
  int af = 0;
  size_t esz = 2;
  {
    size_t bigf = dg35_al((size_t)dgN*dgC*4)*2 + dg35_al((size_t)dgN*dgC2*4);
    if (bigf + fixed <= ws_size){ af = 1; esz = 4; }
  }

  char* base = (char*)d_ws;
  size_t o = 0;
  void* h  = (void*)(base + o); o += dg35_al((size_t)dgN*dgC*esz);
  void* hh = (void*)(base + o); o += dg35_al((size_t)dgN*dgC*esz);
  void* zb = (void*)(base + o); o += dg35_al((size_t)dgN*dgC2*esz);
  float* vn   = (float*)(base + o); o += dg35_al(dgG*dgC*4);
  float* vt   = (float*)(base + o); o += dg35_al(dgG*dgC*4);
  float* zv1  = (float*)(base + o); o += dg35_al(dgG*dgC*4);
  float* zv2  = (float*)(base + o); o += dg35_al(dgG*dgC*4);
  float* st1  = (float*)(base + o); o += dg35_al(8*2*dgC2*4);
  float* ab1  = (float*)(base + o); o += dg35_al(2*dgC2*4);
  float* stH  = (float*)(base + o); o += dg35_al(8*2*dgC*4);
  float* stVV = (float*)(base + o); o += dg35_al(4*dgC*4);
  float* abh  = (float*)(base + o); o += dg35_al(2*dgC*4);
  float* abv1 = (float*)(base + o); o += dg35_al(2*dgC*4);
  float* abv2 = (float*)(base + o); o += dg35_al(2*dgC*4);
  int* deg = (int*)(base + o); o += dg35_al(dgN*4);
  int* cur = (int*)(base + o); o += dg35_al(dgN*4);
  int* off = (int*)(base + o); o += dg35_al((dgN+1)*4);
  int* gs  = (int*)(base + o); o += dg35_al((dgG+1)*4);
  dg35_u32* packed = (dg35_u32*)(base + o); o += dg35_al((size_t)dgE*4);
  short* Wt1h = (short*)(base + o); o += dg35_al(7*256*128*2);
  short* Wt1l = (short*)(base + o); o += dg35_al(7*256*128*2);
  short* Wt2h = (short*)(base + o); o += dg35_al(7*256*128*2);
  short* Wt2l = (short*)(base + o); o += dg35_al(7*256*128*2);
  float* ecomb = (float*)(base + o); o += dg35_al(512*dgC*4);
  int* bsum = (int*)(base + o); o += dg35_al(256*4);
  int* boff = (int*)(base + o); o += dg35_al(256*4);

  if (o > ws_size){
    hipMemsetAsync(d_out, 0x7F, (size_t)out_size*4, stream);
    return;
  }
  float* stV1 = stVV;
  float* stV2 = stVV + 2*dgC;
  void* h2 = zb;
  void* z  = zb;

  // ---- per-call setup ----
  hipMemsetAsync(deg, 0, sizeof(int)*dgN, stream);
  dg35_count  <<<(dgE+255)/256, 256, 0, stream>>>(eidx + dgE, deg, dgE);
  dg35_s1     <<<nsb, 256, 0, stream>>>(deg, bsum, dgN);
  dg35_s2     <<<1, 256, 0, stream>>>(bsum, boff, nsb);
  dg35_s3     <<<nsb, 256, 0, stream>>>(deg, boff, off, cur, dgN);
  dg35_scatter<<<(dgE+255)/256, 256, 0, stream>>>(eidx, eattr, cur, packed, dgE);
  dg35_gstart <<<(dgG+256)/256, 256, 0, stream>>>(batch, gs, dgN, dgG);
  dg35_atom   <<<dgN, dgC, 0, stream>>>(x, aemb, vne, h, af);
  dg35_vninit <<<(dgG*dgC)/256, 256, 0, stream>>>(vne, vn);
  dg35_wconv  <<<1792, 256, 0, stream>>>(cW1, cW2, Wt1h, Wt1l, Wt2h, Wt2l);
  dg35_ecomb  <<<512, 128, 0, stream>>>(bemb, ecomb);

  if (af){
    const int grb = (dgN + 63) / 64;   // 782 row-blocks (BM=64)
    for (int l = 0; l < 7; ++l){
      const float* hin = (const float*)h;
      hipMemsetAsync(st1, 0, 8*2*dgC2*sizeof(float), stream);
      if (l > 0){
        dg35_fin<<<1, 256, 0, stream>>>(stH, ng + (l-1)*dgC, nb + (l-1)*dgC,
                                        abh, 1.f/dgN, dgC, 8);
        hipMemsetAsync(stVV, 0, 4*dgC*sizeof(float), stream);
        dg35_h24<<<(dgN*dgC/4)/256, 256, 0, stream>>>((const float*)h, abh, (float*)h2);
        dg35_vt4<<<dgG, 128, 0, stream>>>((const float*)h2, vn, gs, vt);
        dg35_gemm_v<<<dim3(16,2), 256, 0, stream>>>(vt, vW1 + (l-1)*dgC*dgC,
                                                    vb1 + (l-1)*dgC, (const float*)0,
                                                    zv1, dgG, dgC, dgC, 0);
        dg35_cs4<<<64, 256, 0, stream>>>(zv1, stV1, dgG, dgC);
        dg35_fin<<<1, 256, 0, stream>>>(stV1, vg1 + (l-1)*dgC, vbb1 + (l-1)*dgC,
                                        abv1, 1.f/dgG, dgC, 1);
        dg35_gemm_v<<<dim3(16,2), 256, 0, stream>>>(zv1, vW2 + (l-1)*dgC*dgC,
                                                    vb2 + (l-1)*dgC, abv1,
                                                    zv2, dgG, dgC, dgC, 1);
        dg35_cs4<<<64, 256, 0, stream>>>(zv2, stV2, dgG, dgC);
        dg35_fin<<<1, 256, 0, stream>>>(stV2, vg2 + (l-1)*dgC, vbb2 + (l-1)*dgC,
                                        abv2, 1.f/dgG, dgC, 1);
        dg35_vnfin<<<(dgG*dgC)/256, 256, 0, stream>>>(zv2, abv2, vn);
        dg35_addvn4<<<(dgN*dgC/4)/256, 256, 0, stream>>>((float*)h2, vn, batch);
        hin = (const float*)h2;
      }
      dg35_gb2<<<(dgN+3)/4, 256, 0, stream>>>(hin, packed, off, ecomb, (float*)hh);
      dg35_gemmx<<<dim3(4, grb), 256, 0, stream>>>((const float*)hh,
                                                   Wt1h + l*32768, Wt1l + l*32768,
                                                   cb1 + l*dgC2, (const float*)0,
                                                   (const float*)0, (float*)z, st1,
                                                   dgN, dgC, dgC2, 0, 0);
      dg35_fin<<<1, 256, 0, stream>>>(st1, cg1 + l*dgC2, cbb1 + l*dgC2,
                                      ab1, 1.f/dgN, dgC2, 8);
      hipMemsetAsync(stH, 0, 8*2*dgC*sizeof(float), stream);
      dg35_gemmx<<<dim3(2, grb), 256, 0, stream>>>((const float*)z,
                                                   Wt2h + l*32768, Wt2l + l*32768,
                                                   cb2 + l*dgC, ab1,
                                                   (l==0) ? (const float*)0 : (const float*)h,
                                                   (float*)h, stH,
                                                   dgN, dgC2, dgC, 1, (l==0)?0:1);
    }
    dg35_fin<<<1, 256, 0, stream>>>(stH, ng + 6*dgC, nb + 6*dgC, abh, 1.f/dgN, dgC, 8);
    dg35_out4<<<dgG, 128, 0, stream>>>((const float*)h, abh, gs, out);
  } else {
    // tier-B fallback (bf16 storage, VALU GEMM)
    const int gx = (dgN + 63) / 64;
    for (int l = 0; l < 7; ++l){
      dg35_zero<<<1, 512, 0, stream>>>(st1, stH, stV1, stV2);
      const void* hin = h;
      if (l > 0){
        dg35_colstats<<<128, 256, 0, stream>>>(h, stH, dgN, dgC, af);
        dg35_fin<<<1, 256, 0, stream>>>(stH, ng + (l-1)*dgC, nb + (l-1)*dgC,
                                        abh, 1.f/dgN, dgC, 1);
        dg35_h2<<<(dgN*dgC)/256, 256, 0, stream>>>(h, abh, h2, af);
        dg35_vt<<<dgG, dgC, 0, stream>>>(h2, vn, gs, vt, af);
        dg35_gemm_v<<<dim3(16,2), 256, 0, stream>>>(vt, vW1 + (l-1)*dgC*dgC,
                                                    vb1 + (l-1)*dgC, (const float*)0,
                                                    zv1, dgG, dgC, dgC, 0);
        dg35_cs4<<<64, 256, 0, stream>>>(zv1, stV1, dgG, dgC);
        dg35_fin<<<1, 256, 0, stream>>>(stV1, vg1 + (l-1)*dgC, vbb1 + (l-1)*dgC,
                                        abv1, 1.f/dgG, dgC, 1);
        dg35_gemm_v<<<dim3(16,2), 256, 0, stream>>>(zv1, vW2 + (l-1)*dgC*dgC,
                                                    vb2 + (l-1)*dgC, abv1,
                                                    zv2, dgG, dgC, dgC, 1);
        dg35_cs4<<<64, 256, 0, stream>>>(zv2, stV2, dgG, dgC);
        dg35_fin<<<1, 256, 0, stream>>>(stV2, vg2 + (l-1)*dgC, vbb2 + (l-1)*dgC,
                                        abv2, 1.f/dgG, dgC, 1);
        dg35_vnfin<<<(dgG*dgC)/256, 256, 0, stream>>>(zv2, abv2, vn);
        dg35_addvn<<<dgN, dgC, 0, stream>>>(h2, vn, batch, af);
        hin = h2;
      }
      dg35_gb<<<dgN, dgC, 0, stream>>>(hin, packed, off, bemb, hh, af);
      dg35_gemm_h<<<dim3(gx,4), 256, 0, stream>>>(hh, cW1 + l*dgC*dgC2,
                                                  cb1 + l*dgC2, (const float*)0,
                                                  (const void*)0, z,
                                                  dgN, dgC, dgC2, 0, 0, af);
      dg35_colstats<<<128, 256, 0, stream>>>(z, st1, dgN, dgC2, af);
      dg35_fin<<<1, 256, 0, stream>>>(st1, cg1 + l*dgC2, cbb1 + l*dgC2,
                                      ab1, 1.f/dgN, dgC2, 1);
      dg35_gemm_h<<<dim3(gx,2), 256, 0, stream>>>(z, cW2 + l*dgC2*dgC,
                                                  cb2 + l*dgC, ab1, h, h,
                                                  dgN, dgC2, dgC, 1, (l==0)?0:1, af);
    }
    hipMemsetAsync(stH, 0, sizeof(float)*2*dgC, stream);
    dg35_colstats<<<128, 256, 0, stream>>>(h, stH, dgN, dgC, af);
    dg35_fin<<<1, 256, 0, stream>>>(stH, ng + 6*dgC, nb + 6*dgC, abh, 1.f/dgN, dgC, 1);
    dg35_out<<<dgG, dgC, 0, stream>>>(h, abh, gs, out, af);
  }
}

// Round 16
// 1365.395 us; speedup vs baseline: 1.1572x; 1.0022x over previous
//
#include <hip/hip_runtime.h>

typedef unsigned short dg35_u16;
typedef unsigned int   dg35_u32;

constexpr int dgN  = 50000;
constexpr int dgE  = 400000;
constexpr int dgG  = 1024;
constexpr int dgC  = 128;
constexpr int dgC2 = 256;

typedef __attribute__((ext_vector_type(8))) short dg35_s8v;   // 8 bf16 (4 VGPR)
typedef __attribute__((ext_vector_type(4))) float dg35_f4v;   // MFMA acc

__device__ __forceinline__ float dg35_bf2f(dg35_u16 u){
  return __uint_as_float(((dg35_u32)u) << 16);
}
__device__ __forceinline__ dg35_u16 dg35_f2bf(float f){
  dg35_u32 u = __float_as_uint(f);
  u += 0x7FFFu + ((u >> 16) & 1u);
  return (dg35_u16)(u >> 16);
}
__device__ __forceinline__ float dg35_ldx(const void* p, size_t i, int af){
  return af ? ((const float*)p)[i] : dg35_bf2f(((const dg35_u16*)p)[i]);
}
__device__ __forceinline__ void dg35_stx(void* p, size_t i, int af, float v){
  if (af) ((float*)p)[i] = v; else ((dg35_u16*)p)[i] = dg35_f2bf(v);
}

// Symbol from the harness template; kept but never launched.
__global__ void DeeperGCN_35820027248884_kernel(){}

// ---------------- CSR build ----------------
__global__ void dg35_count(const int* __restrict__ dst, int* __restrict__ deg, int e){
  int j = blockIdx.x*256 + threadIdx.x;
  if (j < e) atomicAdd(&deg[dst[j]], 1);
}

__global__ void dg35_s1(const int* __restrict__ deg, int* __restrict__ bsum, int n){
  __shared__ int sm[256];
  int t = threadIdx.x, b = blockIdx.x;
  int idx = b*256 + t;
  sm[t] = (idx < n) ? deg[idx] : 0;
  __syncthreads();
  for (int s = 128; s > 0; s >>= 1){
    if (t < s) sm[t] += sm[t+s];
    __syncthreads();
  }
  if (t == 0) bsum[b] = sm[0];
}

__global__ void dg35_s2(const int* __restrict__ bsum, int* __restrict__ boff, int nb){
  __shared__ int sm[256];
  int t = threadIdx.x;
  int v = (t < nb) ? bsum[t] : 0;
  sm[t] = v;
  __syncthreads();
  for (int s = 1; s < 256; s <<= 1){
    int u = (t >= s) ? sm[t-s] : 0;
    __syncthreads();
    sm[t] += u;
    __syncthreads();
  }
  if (t < nb) boff[t] = sm[t] - v;
}

__global__ void dg35_s3(const int* __restrict__ deg, const int* __restrict__ boff,
                        int* __restrict__ off, int* __restrict__ cur, int n){
  __shared__ int sm[256];
  int t = threadIdx.x, b = blockIdx.x;
  int idx = b*256 + t;
  int v = (idx < n) ? deg[idx] : 0;
  sm[t] = v;
  __syncthreads();
  for (int s = 1; s < 256; s <<= 1){
    int u = (t >= s) ? sm[t-s] : 0;
    __syncthreads();
    sm[t] += u;
    __syncthreads();
  }
  if (idx < n){
    int e = boff[b] + sm[t] - v;
    off[idx] = e; cur[idx] = e;
  }
  if (idx == 0) off[n] = dgE;
}

__global__ void dg35_scatter(const int* __restrict__ ei, const int* __restrict__ ea,
                             int* __restrict__ cur, dg35_u32* __restrict__ packed, int e){
  int j = blockIdx.x*256 + threadIdx.x;
  if (j >= e) return;
  int s = ei[j], d = ei[e + j];
  dg35_u32 a0 = (dg35_u32)ea[3*j], a1 = (dg35_u32)ea[3*j+1], a2 = (dg35_u32)ea[3*j+2];
  int pos = atomicAdd(&cur[d], 1);
  packed[pos] = (dg35_u32)s | (a0<<17) | (a1<<20) | (a2<<23);
}

__global__ void dg35_gstart(const int* __restrict__ batch, int* __restrict__ gs, int n, int g){
  int i = blockIdx.x*256 + threadIdx.x;
  if (i > g) return;
  if (i == g){ gs[i] = n; return; }
  int lo = 0, hi = n;
  while (lo < hi){ int mid = (lo+hi)>>1; if (batch[mid] < i) lo = mid+1; else hi = mid; }
  gs[i] = lo;
}

// ---------------- encoders / weight prep ----------------
__global__ __launch_bounds__(128)
void dg35_atom(const int* __restrict__ x, const float* __restrict__ aemb,
               const float* __restrict__ vne, void* __restrict__ h, int af){
  int i = blockIdx.x, c = threadIdx.x;
  float acc = vne[c];
  #pragma unroll
  for (int f = 0; f < 9; ++f){
    int idx = x[i*9 + f];
    acc += aemb[(f*128 + idx)*dgC + c];
  }
  dg35_stx(h, (size_t)i*dgC + c, af, acc);
}

__global__ void dg35_vninit(const float* __restrict__ vne, float* __restrict__ vn){
  int i = blockIdx.x*256 + threadIdx.x;
  if (i < dgG*dgC) vn[i] = vne[i & (dgC-1)];
}

// combo table: ecomb[c9][c] = bemb[a0][c] + bemb[8+a1][c] + bemb[16+a2][c]
__global__ __launch_bounds__(128)
void dg35_ecomb(const float* __restrict__ bemb, float* __restrict__ ecomb){
  int c9 = blockIdx.x, t = threadIdx.x;
  int a0 = c9 & 7, a1 = (c9 >> 3) & 7, a2 = (c9 >> 6) & 7;
  ecomb[c9*dgC + t] = bemb[a0*dgC + t] + bemb[(8+a1)*dgC + t] + bemb[(16+a2)*dgC + t];
}

// transpose+convert conv weights to SPLIT bf16 (hi+lo) in [l][n][k] layout
__global__ void dg35_wconv(const float* __restrict__ W1, const float* __restrict__ W2,
                           short* __restrict__ Wt1h, short* __restrict__ Wt1l,
                           short* __restrict__ Wt2h, short* __restrict__ Wt2l){
  int i = blockIdx.x*256 + threadIdx.x;
  constexpr int per = 7*256*128;
  float w;
  short* ph; short* pl; int oidx;
  if (i < per){
    int l = i >> 15;
    int rem = i & 32767;
    int n = rem >> 7;
    int k = rem & 127;
    w = W1[l*32768 + k*256 + n];
    ph = Wt1h; pl = Wt1l; oidx = i;
  } else {
    int j = i - per;
    int l = j >> 15;
    int rem = j & 32767;
    int n = rem >> 8;
    int k = rem & 255;
    w = W2[l*32768 + k*128 + n];
    ph = Wt2h; pl = Wt2l; oidx = j;
  }
  dg35_u16 hi = dg35_f2bf(w);
  float lo = w - dg35_bf2f(hi);
  ph[oidx] = (short)hi;
  pl[oidx] = (short)dg35_f2bf(lo);
}

__global__ void dg35_zero(float* a, float* b, float* c_, float* d){
  int t = threadIdx.x;
  if (t < 512) a[t] = 0.f;
  if (t < 256){ b[t]=0.f; c_[t]=0.f; d[t]=0.f; }
}

// ------------- GENConv softmax aggr: exp-direct (shift-8), 2 ch/lane, 2 edge streams ----
__global__ __launch_bounds__(256)
void dg35_gb2(const float* __restrict__ hin, const dg35_u32* __restrict__ packed,
              const int* __restrict__ off, const float* __restrict__ ecomb,
              float* __restrict__ hh){
  int i = blockIdx.x*4 + (threadIdx.x >> 6);
  if (i >= dgN) return;
  int c = (threadIdx.x & 63) * 2;
  int b0 = off[i], b1 = off[i+1];
  float2 self = *reinterpret_cast<const float2*>(hin + (size_t)i*dgC + c);
  float sA0=0.f, wA0=0.f, sA1=0.f, wA1=0.f;
  float sB0=0.f, wB0=0.f, sB1=0.f, wB1=0.f;
  int p = b0;
  for (; p + 1 < b1; p += 2){
    dg35_u32 pkA = packed[p], pkB = packed[p+1];
    int srcA = (int)(pkA & 0x1FFFFu), srcB = (int)(pkB & 0x1FFFFu);
    float2 hA = *reinterpret_cast<const float2*>(hin + (size_t)srcA*dgC + c);
    float2 hB = *reinterpret_cast<const float2*>(hin + (size_t)srcB*dgC + c);
    float2 eA = *reinterpret_cast<const float2*>(ecomb + (size_t)(pkA>>17)*dgC + c);
    float2 eB = *reinterpret_cast<const float2*>(ecomb + (size_t)(pkB>>17)*dgC + c);
    float msgA0 = fmaxf(hA.x + eA.x, 0.f) + 1e-7f;
    float msgA1 = fmaxf(hA.y + eA.y, 0.f) + 1e-7f;
    float msgB0 = fmaxf(hB.x + eB.x, 0.f) + 1e-7f;
    float msgB1 = fmaxf(hB.y + eB.y, 0.f) + 1e-7f;
    float tA0 = __expf(msgA0 - 8.f), tA1 = __expf(msgA1 - 8.f);
    float tB0 = __expf(msgB0 - 8.f), tB1 = __expf(msgB1 - 8.f);
    sA0 += tA0; wA0 = fmaf(msgA0, tA0, wA0);
    sA1 += tA1; wA1 = fmaf(msgA1, tA1, wA1);
    sB0 += tB0; wB0 = fmaf(msgB0, tB0, wB0);
    sB1 += tB1; wB1 = fmaf(msgB1, tB1, wB1);
  }
  if (p < b1){
    dg35_u32 pkA = packed[p];
    int srcA = (int)(pkA & 0x1FFFFu);
    float2 hA = *reinterpret_cast<const float2*>(hin + (size_t)srcA*dgC + c);
    float2 eA = *reinterpret_cast<const float2*>(ecomb + (size_t)(pkA>>17)*dgC + c);
    float msg0 = fmaxf(hA.x + eA.x, 0.f) + 1e-7f;
    float msg1 = fmaxf(hA.y + eA.y, 0.f) + 1e-7f;
    float t0 = __expf(msg0 - 8.f), t1 = __expf(msg1 - 8.f);
    sA0 += t0; wA0 = fmaf(msg0, t0, wA0);
    sA1 += t1; wA1 = fmaf(msg1, t1, wA1);
  }
  float s0 = sA0 + sB0, w0 = wA0 + wB0;
  float s1 = sA1 + sB1, w1 = wA1 + wB1;
  float2 o;
  o.x = self.x + ((b1 > b0) ? (w0 / (s0 + 1e-16f)) : 0.f);
  o.y = self.y + ((b1 > b0) ? (w1 / (s1 + 1e-16f)) : 0.f);
  *reinterpret_cast<float2*>(hh + (size_t)i*dgC + c) = o;
}

// ---- split-bf16 MFMA GEMM, BM=64, A+B LDS-staged (swizzled), COALESCED staging,
//      prefetch, fused column stats (8-way replicated), XCD chunk swizzle ----
// Staging remap: consecutive lanes read consecutive 16B (one wave instr = 1KB contig).
// A: thread t, piece i in 0..3: row = i*16 + t/16, f32 cols (t&15)*4 .. +3.
// B: thread t, piece j in 0..1: row = j*32 + t/8, short slot t&7 (8 shorts = 16B).
__global__ __launch_bounds__(256)
void dg35_gemmx(const float* __restrict__ A, const short* __restrict__ Whi,
                const short* __restrict__ Wlo, const float* __restrict__ bias,
                const float* __restrict__ ab, const float* __restrict__ res,
                float* __restrict__ Cout, float* __restrict__ st,
                int M, int K, int NC, int trans, int addres){
  __shared__ short Ahi[64*64];   // 8 KB
  __shared__ short Alo[64*64];   // 8 KB
  __shared__ short Bhs[64*64];   // 8 KB
  __shared__ short Bls[64*64];   // 8 KB
  int tid = threadIdx.x;
  // bijective XCD chunk swizzle (m204)
  int nwg = gridDim.x * gridDim.y;
  int lin = blockIdx.y * gridDim.x + blockIdx.x;
  int q8 = nwg >> 3, r8 = nwg & 7;
  int xcd = lin & 7, pos = lin >> 3;
  int wg = (xcd < r8) ? (xcd*(q8+1) + pos) : (r8*(q8+1) + (xcd-r8)*q8 + pos);
  int bn = (wg % gridDim.x) * 64;
  int bm = (wg / gridDim.x) * 64;
  float* stc = st + (size_t)(wg & 7) * 2 * NC;
  int lane = tid & 63;
  int wv = tid >> 6;
  int l15 = lane & 15;
  int l4  = lane >> 4;
  dg35_f4v acc[4] = {};

  // coalesced staging coords
  int rA0  = tid >> 4;          // A base row (piece adds i*16)
  int colf = (tid & 15) * 4;    // f32 col within 64-wide tile
  int c8   = colf >> 3;         // pre-swizzle 16B-slot index
  int halfo = ((colf >> 2) & 1) * 4;  // short offset within slot
  int rB0 = tid >> 3;           // B base row (piece adds j*32)
  int sB  = tid & 7;            // B pre-swizzle slot

  float4 va[4];
  #pragma unroll
  for (int i = 0; i < 4; ++i){
    int row = bm + i*16 + rA0;
    va[i] = (row < M) ? *reinterpret_cast<const float4*>(A + (size_t)row*K + colf)
                      : make_float4(0.f,0.f,0.f,0.f);
  }

  for (int k0 = 0; k0 < K; k0 += 64){
    // issue B loads (coalesced; latency overlaps A conversion)
    uint4 bth[2], btl[2];
    #pragma unroll
    for (int j = 0; j < 2; ++j){
      int rowB = j*32 + rB0;
      size_t wo = (size_t)(bn + rowB)*K + k0 + sB*8;
      bth[j] = *reinterpret_cast<const uint4*>(Whi + wo);
      btl[j] = *reinterpret_cast<const uint4*>(Wlo + wo);
    }
    // BN coefficients for this thread's 4 columns (shared across pieces)
    float aK[4], bK[4];
    if (trans){
      #pragma unroll
      for (int e = 0; e < 4; ++e){
        aK[e] = ab[k0 + colf + e];
        bK[e] = ab[K + k0 + colf + e];
      }
    }
    // convert A pieces -> swizzled split-bf16 LDS (8B per piece per buffer)
    #pragma unroll
    for (int i = 0; i < 4; ++i){
      int rowA = i*16 + rA0;
      float xv[4] = {va[i].x, va[i].y, va[i].z, va[i].w};
      if (trans){
        #pragma unroll
        for (int e = 0; e < 4; ++e) xv[e] = fmaxf(xv[e]*aK[e] + bK[e], 0.f);
      }
      unsigned hp0, hp1, lp0, lp1;
      {
        dg35_u16 h0 = dg35_f2bf(xv[0]), h1 = dg35_f2bf(xv[1]);
        dg35_u16 l0 = dg35_f2bf(xv[0] - dg35_bf2f(h0));
        dg35_u16 l1 = dg35_f2bf(xv[1] - dg35_bf2f(h1));
        hp0 = (dg35_u32)h0 | ((dg35_u32)h1 << 16);
        lp0 = (dg35_u32)l0 | ((dg35_u32)l1 << 16);
      }
      {
        dg35_u16 h0 = dg35_f2bf(xv[2]), h1 = dg35_f2bf(xv[3]);
        dg35_u16 l0 = dg35_f2bf(xv[2] - dg35_bf2f(h0));
        dg35_u16 l1 = dg35_f2bf(xv[3] - dg35_bf2f(h1));
        hp1 = (dg35_u32)h0 | ((dg35_u32)h1 << 16);
        lp1 = (dg35_u32)l0 | ((dg35_u32)l1 << 16);
      }
      int off = rowA*64 + ((c8 ^ (rowA & 7)) << 3) + halfo;
      *reinterpret_cast<uint2*>(&Ahi[off]) = make_uint2(hp0, hp1);
      *reinterpret_cast<uint2*>(&Alo[off]) = make_uint2(lp0, lp1);
    }
    // write B to swizzled LDS (one full 16B slot per piece)
    #pragma unroll
    for (int j = 0; j < 2; ++j){
      int rowB = j*32 + rB0;
      int offB = rowB*64 + ((sB ^ (rowB & 7)) << 3);
      *reinterpret_cast<uint4*>(&Bhs[offB]) = bth[j];
      *reinterpret_cast<uint4*>(&Bls[offB]) = btl[j];
    }
    __syncthreads();
    // prefetch next A tile (overlaps MFMA; invalid rows stay zero from prologue)
    if (k0 + 64 < K){
      #pragma unroll
      for (int i = 0; i < 4; ++i){
        int row = bm + i*16 + rA0;
        if (row < M)
          va[i] = *reinterpret_cast<const float4*>(A + (size_t)row*K + k0 + 64 + colf);
      }
    }
    // MFMA over 2 K-steps of 32, A and B both from LDS (read side unchanged)
    #pragma unroll
    for (int ks = 0; ks < 2; ++ks){
      dg35_s8v bh[4], bl[4];
      #pragma unroll
      for (int nf = 0; nf < 4; ++nf){
        int n = nf*16 + l15;
        int slot = (ks*4 + l4) ^ (n & 7);
        bh[nf] = *reinterpret_cast<const dg35_s8v*>(&Bhs[n*64 + slot*8]);
        bl[nf] = *reinterpret_cast<const dg35_s8v*>(&Bls[n*64 + slot*8]);
      }
      int row = wv*16 + l15;
      int slotA = (ks*4 + l4) ^ (row & 7);
      dg35_s8v ah = *reinterpret_cast<const dg35_s8v*>(&Ahi[row*64 + slotA*8]);
      dg35_s8v al = *reinterpret_cast<const dg35_s8v*>(&Alo[row*64 + slotA*8]);
      #pragma unroll
      for (int nf = 0; nf < 4; ++nf){
        acc[nf] = __builtin_amdgcn_mfma_f32_16x16x32_bf16(ah, bh[nf], acc[nf], 0, 0, 0);
        acc[nf] = __builtin_amdgcn_mfma_f32_16x16x32_bf16(al, bh[nf], acc[nf], 0, 0, 0);
        acc[nf] = __builtin_amdgcn_mfma_f32_16x16x32_bf16(ah, bl[nf], acc[nf], 0, 0, 0);
      }
    }
    __syncthreads();
  }
  // epilogue: write + per-lane col partial stats
  float s[4] = {0.f,0.f,0.f,0.f}, q[4] = {0.f,0.f,0.f,0.f};
  #pragma unroll
  for (int e = 0; e < 4; ++e){
    int rr = bm + wv*16 + l4*4 + e;
    if (rr >= M) continue;
    #pragma unroll
    for (int nf = 0; nf < 4; ++nf){
      int cc = bn + nf*16 + l15;
      float v = acc[nf][e] + bias[cc];
      size_t idx = (size_t)rr*NC + cc;
      if (addres) v += res[idx];
      Cout[idx] = v;
      s[nf] += v; q[nf] += v*v;
    }
  }
  #pragma unroll
  for (int nf = 0; nf < 4; ++nf){
    s[nf] += __shfl_xor(s[nf], 16); s[nf] += __shfl_xor(s[nf], 32);
    q[nf] += __shfl_xor(q[nf], 16); q[nf] += __shfl_xor(q[nf], 32);
  }
  __syncthreads();
  float* red = (float*)Ahi;
  if (l4 == 0){
    #pragma unroll
    for (int nf = 0; nf < 4; ++nf){
      red[wv*128 + nf*16 + l15] = s[nf];
      red[wv*128 + 64 + nf*16 + l15] = q[nf];
    }
  }
  __syncthreads();
  if (tid < 64){
    float S = red[tid] + red[128+tid] + red[256+tid] + red[384+tid];
    float Q = red[64+tid] + red[192+tid] + red[320+tid] + red[448+tid];
    atomicAdd(&stc[bn + tid], S);
    atomicAdd(&stc[NC + bn + tid], Q);
  }
}

// -------- VALU GEMM (dual-precision) — tier-B fallback only --------
__global__ __launch_bounds__(256)
void dg35_gemm_h(const void* __restrict__ A, const float* __restrict__ W,
                 const float* __restrict__ bias, const float* __restrict__ ab,
                 const void* __restrict__ res, void* __restrict__ Cout,
                 int M, int K, int NC, int trans, int addres, int af){
  __shared__ float At[32][65];
  __shared__ float Bt[32][64];
  int bm = blockIdx.x * 64;
  int bn = blockIdx.y * 64;
  int tid = threadIdx.x;
  int tx = tid & 15, ty = tid >> 4;
  float acc[4][4];
  #pragma unroll
  for (int i2 = 0; i2 < 4; ++i2)
    #pragma unroll
    for (int j2 = 0; j2 < 4; ++j2) acc[i2][j2] = 0.f;

  for (int k0 = 0; k0 < K; k0 += 32){
    int r = tid >> 3;
    int kq = (tid & 7) * 4;
    #pragma unroll
    for (int half = 0; half < 2; ++half){
      int rr = r + half*32;
      int grow = bm + rr;
      float vv[4] = {0.f, 0.f, 0.f, 0.f};
      if (grow < M){
        if (af){
          float4 v4 = *reinterpret_cast<const float4*>((const float*)A + (size_t)grow*K + k0 + kq);
          vv[0] = v4.x; vv[1] = v4.y; vv[2] = v4.z; vv[3] = v4.w;
        } else {
          ushort4 v4 = *reinterpret_cast<const ushort4*>((const dg35_u16*)A + (size_t)grow*K + k0 + kq);
          vv[0] = dg35_bf2f(v4.x); vv[1] = dg35_bf2f(v4.y);
          vv[2] = dg35_bf2f(v4.z); vv[3] = dg35_bf2f(v4.w);
        }
      }
      #pragma unroll
      for (int i2 = 0; i2 < 4; ++i2){
        float xv = vv[i2];
        if (trans){
          int kk = k0 + kq + i2;
          xv = fmaxf(xv*ab[kk] + ab[K + kk], 0.f);
        }
        At[kq + i2][rr] = xv;
      }
    }
    {
      int kr = tid >> 3;
      int cq = (tid & 7) * 8;
      const float* wp = W + (size_t)(k0 + kr)*NC + bn + cq;
      #pragma unroll
      for (int i2 = 0; i2 < 8; ++i2) Bt[kr][cq + i2] = wp[i2];
    }
    __syncthreads();
    #pragma unroll
    for (int kk = 0; kk < 32; ++kk){
      float a4[4], b4[4];
      #pragma unroll
      for (int i2 = 0; i2 < 4; ++i2) a4[i2] = At[kk][ty*4 + i2];
      #pragma unroll
      for (int j2 = 0; j2 < 4; ++j2) b4[j2] = Bt[kk][tx*4 + j2];
      #pragma unroll
      for (int i2 = 0; i2 < 4; ++i2)
        #pragma unroll
        for (int j2 = 0; j2 < 4; ++j2)
          acc[i2][j2] += a4[i2]*b4[j2];
    }
    __syncthreads();
  }
  #pragma unroll
  for (int i2 = 0; i2 < 4; ++i2){
    int rr = bm + ty*4 + i2;
    if (rr >= M) continue;
    #pragma unroll
    for (int j2 = 0; j2 < 4; ++j2){
      int cc = bn + tx*4 + j2;
      float v = acc[i2][j2] + bias[cc];
      size_t idx = (size_t)rr*NC + cc;
      if (addres) v += dg35_ldx(res, idx, af);
      dg35_stx(Cout, idx, af, v);
    }
  }
}

// -------- GEMM, A f32, W f32, f32 out (virtual-node MLP, M=1024) --------
__global__ __launch_bounds__(256)
void dg35_gemm_v(const float* __restrict__ A, const float* __restrict__ W,
                 const float* __restrict__ bias, const float* __restrict__ ab,
                 float* __restrict__ Cout, int M, int K, int NC, int trans){
  __shared__ float At[32][65];
  __shared__ float Bt[32][64];
  int bm = blockIdx.x * 64;
  int bn = blockIdx.y * 64;
  int tid = threadIdx.x;
  int tx = tid & 15, ty = tid >> 4;
  float acc[4][4];
  #pragma unroll
  for (int i2 = 0; i2 < 4; ++i2)
    #pragma unroll
    for (int j2 = 0; j2 < 4; ++j2) acc[i2][j2] = 0.f;

  for (int k0 = 0; k0 < K; k0 += 32){
    int r = tid >> 3;
    int kq = (tid & 7) * 4;
    #pragma unroll
    for (int half = 0; half < 2; ++half){
      int rr = r + half*32;
      int grow = bm + rr;
      float vv[4] = {0.f, 0.f, 0.f, 0.f};
      if (grow < M){
        float4 v4 = *reinterpret_cast<const float4*>(A + (size_t)grow*K + k0 + kq);
        vv[0] = v4.x; vv[1] = v4.y; vv[2] = v4.z; vv[3] = v4.w;
      }
      #pragma unroll
      for (int i2 = 0; i2 < 4; ++i2){
        float xv = vv[i2];
        if (trans){
          int kk = k0 + kq + i2;
          xv = fmaxf(xv*ab[kk] + ab[K + kk], 0.f);
        }
        At[kq + i2][rr] = xv;
      }
    }
    {
      int kr = tid >> 3;
      int cq = (tid & 7) * 8;
      const float* wp = W + (size_t)(k0 + kr)*NC + bn + cq;
      #pragma unroll
      for (int i2 = 0; i2 < 8; ++i2) Bt[kr][cq + i2] = wp[i2];
    }
    __syncthreads();
    #pragma unroll
    for (int kk = 0; kk < 32; ++kk){
      float a4[4], b4[4];
      #pragma unroll
      for (int i2 = 0; i2 < 4; ++i2) a4[i2] = At[kk][ty*4 + i2];
      #pragma unroll
      for (int j2 = 0; j2 < 4; ++j2) b4[j2] = Bt[kk][tx*4 + j2];
      #pragma unroll
      for (int i2 = 0; i2 < 4; ++i2)
        #pragma unroll
        for (int j2 = 0; j2 < 4; ++j2)
          acc[i2][j2] += a4[i2]*b4[j2];
    }
    __syncthreads();
  }
  #pragma unroll
  for (int i2 = 0; i2 < 4; ++i2){
    int rr = bm + ty*4 + i2;
    if (rr >= M) continue;
    #pragma unroll
    for (int j2 = 0; j2 < 4; ++j2){
      int cc = bn + tx*4 + j2;
      Cout[(size_t)rr*NC + cc] = acc[i2][j2] + bias[cc];
    }
  }
}

// ---------------- BN statistics (small f32 buffers: zv1/zv2) ----------------
__global__ __launch_bounds__(256)
void dg35_cs4(const float* __restrict__ Z, float* __restrict__ st, int n, int ncols){
  int t = threadIdx.x;
  int lpr = ncols >> 2;
  int rl = t / lpr;
  int rpb = 256 / lpr;
  int cq = (t - rl*lpr) * 4;
  float4 s = make_float4(0.f,0.f,0.f,0.f);
  float4 q = make_float4(0.f,0.f,0.f,0.f);
  for (int rr = blockIdx.x*rpb + rl; rr < n; rr += gridDim.x*rpb){
    float4 v = *reinterpret_cast<const float4*>(Z + (size_t)rr*ncols + cq);
    s.x += v.x; s.y += v.y; s.z += v.z; s.w += v.w;
    q.x += v.x*v.x; q.y += v.y*v.y; q.z += v.z*v.z; q.w += v.w*v.w;
  }
  __shared__ float sm[256*8];
  float* my = &sm[t*8];
  my[0]=s.x; my[1]=s.y; my[2]=s.z; my[3]=s.w;
  my[4]=q.x; my[5]=q.y; my[6]=q.z; my[7]=q.w;
  __syncthreads();
  if (rl == 0){
    float a[8];
    #pragma unroll
    for (int d = 0; d < 8; ++d) a[d] = my[d];
    for (int j = 1; j < rpb; ++j){
      const float* o2 = &sm[(t + j*lpr)*8];
      #pragma unroll
      for (int d = 0; d < 8; ++d) a[d] += o2[d];
    }
    #pragma unroll
    for (int d = 0; d < 4; ++d) atomicAdd(&st[cq + d], a[d]);
    #pragma unroll
    for (int d = 0; d < 4; ++d) atomicAdd(&st[ncols + cq + d], a[4 + d]);
  }
}

// tier-B fallback colstats
__global__ void dg35_colstats(const void* __restrict__ Z, float* __restrict__ st,
                              int n, int ncols, int af){
  int tid = threadIdx.x;
  int c = tid & (ncols - 1);
  int rl = tid / ncols;
  int rpb = 256 / ncols;
  float s = 0.f, q = 0.f;
  for (int rr = blockIdx.x*rpb + rl; rr < n; rr += gridDim.x*rpb){
    float v = dg35_ldx(Z, (size_t)rr*ncols + c, af);
    s += v; q += v*v;
  }
  atomicAdd(&st[c], s);
  atomicAdd(&st[ncols + c], q);
}

// finalize BN affine from (possibly replicated) stats
__global__ void dg35_fin(const float* __restrict__ st, const float* __restrict__ g,
                         const float* __restrict__ b, float* __restrict__ ab,
                         float inv_n, int ncols, int ncopy){
  int c = threadIdx.x + blockIdx.x*256;
  if (c >= ncols) return;
  float m = 0.f, q = 0.f;
  for (int k = 0; k < ncopy; ++k){
    m += st[(size_t)k*2*ncols + c];
    q += st[(size_t)k*2*ncols + ncols + c];
  }
  m *= inv_n;
  float var = q*inv_n - m*m;
  float rstd = rsqrtf(var + 1e-5f);
  float a = g[c]*rstd;
  ab[c] = a;
  ab[ncols + c] = b[c] - m*a;
}

// ---------------- elementwise / segment ops ----------------
__global__ void dg35_h24(const float* __restrict__ h, const float* __restrict__ ab,
                         float* __restrict__ h2){
  int i = blockIdx.x*256 + threadIdx.x;
  int c = (i & 31) * 4;
  float4 v = reinterpret_cast<const float4*>(h)[i];
  v.x = fmaxf(v.x*ab[c+0] + ab[dgC+c+0], 0.f);
  v.y = fmaxf(v.y*ab[c+1] + ab[dgC+c+1], 0.f);
  v.z = fmaxf(v.z*ab[c+2] + ab[dgC+c+2], 0.f);
  v.w = fmaxf(v.w*ab[c+3] + ab[dgC+c+3], 0.f);
  reinterpret_cast<float4*>(h2)[i] = v;
}

__global__ void dg35_h2(const void* __restrict__ h, const float* __restrict__ ab,
                        void* __restrict__ h2, int af){
  int i = blockIdx.x*256 + threadIdx.x;
  int c = i & (dgC-1);
  dg35_stx(h2, i, af, fmaxf(dg35_ldx(h, i, af)*ab[c] + ab[dgC + c], 0.f));
}

__global__ __launch_bounds__(128)
void dg35_vt4(const float* __restrict__ h2, const float* __restrict__ vn,
              const int* __restrict__ gs, float* __restrict__ vt){
  int g = blockIdx.x, t = threadIdx.x;
  int rl = t >> 5, cl = t & 31;
  int cq = cl*4;
  int r0 = gs[g], r1 = gs[g+1];
  float4 s = make_float4(0.f,0.f,0.f,0.f);
  for (int rr = r0 + rl; rr < r1; rr += 4){
    float4 v = *reinterpret_cast<const float4*>(h2 + (size_t)rr*dgC + cq);
    s.x += v.x; s.y += v.y; s.z += v.z; s.w += v.w;
  }
  __shared__ float4 sm[128];
  sm[t] = s;
  __syncthreads();
  if (rl == 0){
    float4 a = sm[cl], b = sm[32+cl], c4 = sm[64+cl], d = sm[96+cl];
    float4 vb = *reinterpret_cast<const float4*>(vn + (size_t)g*dgC + cq);
    float4 o;
    o.x = a.x+b.x+c4.x+d.x + vb.x;
    o.y = a.y+b.y+c4.y+d.y + vb.y;
    o.z = a.z+b.z+c4.z+d.z + vb.z;
    o.w = a.w+b.w+c4.w+d.w + vb.w;
    *reinterpret_cast<float4*>(vt + (size_t)g*dgC + cq) = o;
  }
}

__global__ __launch_bounds__(128)
void dg35_vt(const void* __restrict__ h2, const float* __restrict__ vn,
             const int* __restrict__ gs, float* __restrict__ vt, int af){
  int g = blockIdx.x, c = threadIdx.x;
  float s = 0.f;
  int r0 = gs[g], r1 = gs[g+1];
  for (int rr = r0; rr < r1; ++rr) s += dg35_ldx(h2, (size_t)rr*dgC + c, af);
  vt[g*dgC + c] = s + vn[g*dgC + c];
}

__global__ void dg35_vnfin(const float* __restrict__ z2, const float* __restrict__ ab,
                           float* __restrict__ vn){
  int i = blockIdx.x*256 + threadIdx.x;
  int c = i & (dgC-1);
  vn[i] = fmaxf(z2[i]*ab[c] + ab[dgC + c], 0.f);
}

__global__ void dg35_addvn4(float* __restrict__ h2, const float* __restrict__ vn,
                            const int* __restrict__ batch){
  int i = blockIdx.x*256 + threadIdx.x;
  int row = i >> 5;
  int cl = i & 31;
  float4 v = reinterpret_cast<float4*>(h2)[i];
  float4 a = reinterpret_cast<const float4*>(vn)[batch[row]*32 + cl];
  v.x += a.x; v.y += a.y; v.z += a.z; v.w += a.w;
  reinterpret_cast<float4*>(h2)[i] = v;
}

__global__ __launch_bounds__(128)
void dg35_addvn(void* __restrict__ h2, const float* __restrict__ vn,
                const int* __restrict__ batch, int af){
  int i = blockIdx.x, c = threadIdx.x;
  size_t idx = (size_t)i*dgC + c;
  dg35_stx(h2, idx, af, dg35_ldx(h2, idx, af) + vn[batch[i]*dgC + c]);
}

__global__ __launch_bounds__(128)
void dg35_out4(const float* __restrict__ h, const float* __restrict__ ab,
               const int* __restrict__ gs, float* __restrict__ out){
  int g = blockIdx.x, t = threadIdx.x;
  int rl = t >> 5, cl = t & 31;
  int cq = cl*4;
  int r0 = gs[g], r1 = gs[g+1];
  float4 s = make_float4(0.f,0.f,0.f,0.f);
  for (int rr = r0 + rl; rr < r1; rr += 4){
    float4 v = *reinterpret_cast<const float4*>(h + (size_t)rr*dgC + cq);
    s.x += v.x; s.y += v.y; s.z += v.z; s.w += v.w;
  }
  __shared__ float4 sm[128];
  sm[t] = s;
  __syncthreads();
  if (rl == 0){
    float4 a4 = sm[cl], b4 = sm[32+cl], c4 = sm[64+cl], d4 = sm[96+cl];
    float cnt = (float)(r1 - r0);
    float4 o;
    float S;
    S = a4.x+b4.x+c4.x+d4.x; o.x = ab[cq+0]*S + ab[dgC+cq+0]*cnt;
    S = a4.y+b4.y+c4.y+d4.y; o.y = ab[cq+1]*S + ab[dgC+cq+1]*cnt;
    S = a4.z+b4.z+c4.z+d4.z; o.z = ab[cq+2]*S + ab[dgC+cq+2]*cnt;
    S = a4.w+b4.w+c4.w+d4.w; o.w = ab[cq+3]*S + ab[dgC+cq+3]*cnt;
    *reinterpret_cast<float4*>(out + (size_t)g*dgC + cq) = o;
  }
}

// tier-B fallback pieces
__global__ __launch_bounds__(128)
void dg35_gb(const void* __restrict__ hin, const dg35_u32* __restrict__ packed,
             const int* __restrict__ off, const float* __restrict__ bemb,
             void* __restrict__ hh, int af){
  int i = blockIdx.x, c = threadIdx.x;
  int b0 = off[i], b1 = off[i+1];
  float m = -3.0e38f, s = 0.f, w = 0.f;
  for (int p = b0; p < b1; ++p){
    dg35_u32 pk = packed[p];
    int src = (int)(pk & 0x1FFFFu);
    float e = bemb[((pk>>17)&7)*dgC + c] + bemb[(8+((pk>>20)&7))*dgC + c]
            + bemb[(16+((pk>>23)&7))*dgC + c];
    float msg = fmaxf(dg35_ldx(hin, (size_t)src*dgC + c, af) + e, 0.f) + 1e-7f;
    float mn = fmaxf(m, msg);
    float sc = __expf(m - mn), t2 = __expf(msg - mn);
    s = s*sc + t2; w = w*sc + msg*t2; m = mn;
  }
  float agg = (b1 > b0) ? (w / (s + 1e-16f)) : 0.f;
  float self = dg35_ldx(hin, (size_t)i*dgC + c, af);
  dg35_stx(hh, (size_t)i*dgC + c, af, self + agg);
}

__global__ __launch_bounds__(128)
void dg35_out(const void* __restrict__ h, const float* __restrict__ ab,
              const int* __restrict__ gs, float* __restrict__ out, int af){
  int g = blockIdx.x, c = threadIdx.x;
  float a = ab[c], b = ab[dgC + c];
  float s = 0.f;
  int r0 = gs[g], r1 = gs[g+1];
  for (int rr = r0; rr < r1; ++rr) s += dg35_ldx(h, (size_t)rr*dgC + c, af)*a + b;
  out[g*dgC + c] = s;
}

static inline size_t dg35_al(size_t x){ return (x + 255) & ~(size_t)255; }

extern "C" void kernel_launch(void* const* d_in, const int* in_sizes, int n_in,
                              void* d_out, int out_size, void* d_ws, size_t ws_size,
                              hipStream_t stream)
{
  const int*   x     = (const int*)d_in[0];
  const int*   eattr = (const int*)d_in[1];
  const int*   eidx  = (const int*)d_in[2];
  const int*   batch = (const int*)d_in[3];
  const float* aemb  = (const float*)d_in[4];
  const float* bemb  = (const float*)d_in[5];
  const float* vne   = (const float*)d_in[6];
  const float* cW1   = (const float*)d_in[7];
  const float* cb1   = (const float*)d_in[8];
  const float* cg1   = (const float*)d_in[9];
  const float* cbb1  = (const float*)d_in[10];
  const float* cW2   = (const float*)d_in[11];
  const float* cb2   = (const float*)d_in[12];
  const float* ng    = (const float*)d_in[13];
  const float* nb    = (const float*)d_in[14];
  const float* vW1   = (const float*)d_in[15];
  const float* vb1   = (const float*)d_in[16];
  const float* vg1   = (const float*)d_in[17];
  const float* vbb1  = (const float*)d_in[18];
  const float* vW2   = (const float*)d_in[19];
  const float* vb2   = (const float*)d_in[20];
  const float* vg2   = (const float*)d_in[21];
  const float* vbb2  = (const float*)d_in[22];
  float* out = (float*)d_out;

  const int nsb = (dgN + 255) / 256;

  const size_t fixed =
      dg35_al(dgG*dgC*4)*4 +
      dg35_al(8*2*dgC2*4) + dg35_al(2*dgC2*4) +
      dg35_al(8*2*dgC*4) +
      dg35_al(4*dgC*4) +
      dg35_al(2*dgC*4)*3 +
      dg35_al(dgN*4)*2 + dg35_al((dgN+1)*4) +
      dg35_al((dgG+1)*4) +
      dg35_al((size_t)dgE*4) +
      dg35_al(7*256*128*2)*4 +
      dg35_al(512*dgC*4) +
      dg35_al(256*4)*2;
  int af = 0;
  size_t esz = 2;
  {
    size_t bigf = dg35_al((size_t)dgN*dgC*4)*2 + dg35_al((size_t)dgN*dgC2*4);
    if (bigf + fixed <= ws_size){ af = 1; esz = 4; }
  }

  char* base = (char*)d_ws;
  size_t o = 0;
  void* h  = (void*)(base + o); o += dg35_al((size_t)dgN*dgC*esz);
  void* hh = (void*)(base + o); o += dg35_al((size_t)dgN*dgC*esz);
  void* zb = (void*)(base + o); o += dg35_al((size_t)dgN*dgC2*esz);
  float* vn   = (float*)(base + o); o += dg35_al(dgG*dgC*4);
  float* vt   = (float*)(base + o); o += dg35_al(dgG*dgC*4);
  float* zv1  = (float*)(base + o); o += dg35_al(dgG*dgC*4);
  float* zv2  = (float*)(base + o); o += dg35_al(dgG*dgC*4);
  float* st1  = (float*)(base + o); o += dg35_al(8*2*dgC2*4);
  float* ab1  = (float*)(base + o); o += dg35_al(2*dgC2*4);
  float* stH  = (float*)(base + o); o += dg35_al(8*2*dgC*4);
  float* stVV = (float*)(base + o); o += dg35_al(4*dgC*4);
  float* abh  = (float*)(base + o); o += dg35_al(2*dgC*4);
  float* abv1 = (float*)(base + o); o += dg35_al(2*dgC*4);
  float* abv2 = (float*)(base + o); o += dg35_al(2*dgC*4);
  int* deg = (int*)(base + o); o += dg35_al(dgN*4);
  int* cur = (int*)(base + o); o += dg35_al(dgN*4);
  int* off = (int*)(base + o); o += dg35_al((dgN+1)*4);
  int* gs  = (int*)(base + o); o += dg35_al((dgG+1)*4);
  dg35_u32* packed = (dg35_u32*)(base + o); o += dg35_al((size_t)dgE*4);
  short* Wt1h = (short*)(base + o); o += dg35_al(7*256*128*2);
  short* Wt1l = (short*)(base + o); o += dg35_al(7*256*128*2);
  short* Wt2h = (short*)(base + o); o += dg35_al(7*256*128*2);
  short* Wt2l = (short*)(base + o); o += dg35_al(7*256*128*2);
  float* ecomb = (float*)(base + o); o += dg35_al(512*dgC*4);
  int* bsum = (int*)(base + o); o += dg35_al(256*4);
  int* boff = (int*)(base + o); o += dg35_al(256*4);

  if (o > ws_size){
    hipMemsetAsync(d_out, 0x7F, (size_t)out_size*4, stream);
    return;
  }
  float* stV1 = stVV;
  float* stV2 = stVV + 2*dgC;
  void* h2 = zb;
  void* z  = zb;

  // ---- per-call setup ----
  hipMemsetAsync(deg, 0, sizeof(int)*dgN, stream);
  dg35_count  <<<(dgE+255)/256, 256, 0, stream>>>(eidx + dgE, deg, dgE);
  dg35_s1     <<<nsb, 256, 0, stream>>>(deg, bsum, dgN);
  dg35_s2     <<<1, 256, 0, stream>>>(bsum, boff, nsb);
  dg35_s3     <<<nsb, 256, 0, stream>>>(deg, boff, off, cur, dgN);
  dg35_scatter<<<(dgE+255)/256, 256, 0, stream>>>(eidx, eattr, cur, packed, dgE);
  dg35_gstart <<<(dgG+256)/256, 256, 0, stream>>>(batch, gs, dgN, dgG);
  dg35_atom   <<<dgN, dgC, 0, stream>>>(x, aemb, vne, h, af);
  dg35_vninit <<<(dgG*dgC)/256, 256, 0, stream>>>(vne, vn);
  dg35_wconv  <<<1792, 256, 0, stream>>>(cW1, cW2, Wt1h, Wt1l, Wt2h, Wt2l);
  dg35_ecomb  <<<512, 128, 0, stream>>>(bemb, ecomb);

  if (af){
    const int grb = (dgN + 63) / 64;   // 782 row-blocks (BM=64)
    for (int l = 0; l < 7; ++l){
      const float* hin = (const float*)h;
      hipMemsetAsync(st1, 0, 8*2*dgC2*sizeof(float), stream);
      if (l > 0){
        dg35_fin<<<1, 256, 0, stream>>>(stH, ng + (l-1)*dgC, nb + (l-1)*dgC,
                                        abh, 1.f/dgN, dgC, 8);
        hipMemsetAsync(stVV, 0, 4*dgC*sizeof(float), stream);
        dg35_h24<<<(dgN*dgC/4)/256, 256, 0, stream>>>((const float*)h, abh, (float*)h2);
        dg35_vt4<<<dgG, 128, 0, stream>>>((const float*)h2, vn, gs, vt);
        dg35_gemm_v<<<dim3(16,2), 256, 0, stream>>>(vt, vW1 + (l-1)*dgC*dgC,
                                                    vb1 + (l-1)*dgC, (const float*)0,
                                                    zv1, dgG, dgC, dgC, 0);
        dg35_cs4<<<64, 256, 0, stream>>>(zv1, stV1, dgG, dgC);
        dg35_fin<<<1, 256, 0, stream>>>(stV1, vg1 + (l-1)*dgC, vbb1 + (l-1)*dgC,
                                        abv1, 1.f/dgG, dgC, 1);
        dg35_gemm_v<<<dim3(16,2), 256, 0, stream>>>(zv1, vW2 + (l-1)*dgC*dgC,
                                                    vb2 + (l-1)*dgC, abv1,
                                                    zv2, dgG, dgC, dgC, 1);
        dg35_cs4<<<64, 256, 0, stream>>>(zv2, stV2, dgG, dgC);
        dg35_fin<<<1, 256, 0, stream>>>(stV2, vg2 + (l-1)*dgC, vbb2 + (l-1)*dgC,
                                        abv2, 1.f/dgG, dgC, 1);
        dg35_vnfin<<<(dgG*dgC)/256, 256, 0, stream>>>(zv2, abv2, vn);
        dg35_addvn4<<<(dgN*dgC/4)/256, 256, 0, stream>>>((float*)h2, vn, batch);
        hin = (const float*)h2;
      }
      dg35_gb2<<<(dgN+3)/4, 256, 0, stream>>>(hin, packed, off, ecomb, (float*)hh);
      dg35_gemmx<<<dim3(4, grb), 256, 0, stream>>>((const float*)hh,
                                                   Wt1h + l*32768, Wt1l + l*32768,
                                                   cb1 + l*dgC2, (const float*)0,
                                                   (const float*)0, (float*)z, st1,
                                                   dgN, dgC, dgC2, 0, 0);
      dg35_fin<<<1, 256, 0, stream>>>(st1, cg1 + l*dgC2, cbb1 + l*dgC2,
                                      ab1, 1.f/dgN, dgC2, 8);
      hipMemsetAsync(stH, 0, 8*2*dgC*sizeof(float), stream);
      dg35_gemmx<<<dim3(2, grb), 256, 0, stream>>>((const float*)z,
                                                   Wt2h + l*32768, Wt2l + l*32768,
                                                   cb2 + l*dgC, ab1,
                                                   (l==0) ? (const float*)0 : (const float*)h,
                                                   (float*)h, stH,
                                                   dgN, dgC2, dgC, 1, (l==0)?0:1);
    }
    dg35_fin<<<1, 256, 0, stream>>>(stH, ng + 6*dgC, nb + 6*dgC, abh, 1.f/dgN, dgC, 8);
    dg35_out4<<<dgG, 128, 0, stream>>>((const float*)h, abh, gs, out);
  } else {
    // tier-B fallback (bf16 storage, VALU GEMM)
    const int gx = (dgN + 63) / 64;
    for (int l = 0; l < 7; ++l){
      dg35_zero<<<1, 512, 0, stream>>>(st1, stH, stV1, stV2);
      const void* hin = h;
      if (l > 0){
        dg35_colstats<<<128, 256, 0, stream>>>(h, stH, dgN, dgC, af);
        dg35_fin<<<1, 256, 0, stream>>>(stH, ng + (l-1)*dgC, nb + (l-1)*dgC,
                                        abh, 1.f/dgN, dgC, 1);
        dg35_h2<<<(dgN*dgC)/256, 256, 0, stream>>>(h, abh, h2, af);
        dg35_vt<<<dgG, dgC, 0, stream>>>(h2, vn, gs, vt, af);
        dg35_gemm_v<<<dim3(16,2), 256, 0, stream>>>(vt, vW1 + (l-1)*dgC*dgC,
                                                    vb1 + (l-1)*dgC, (const float*)0,
                                                    zv1, dgG, dgC, dgC, 0);
        dg35_cs4<<<64, 256, 0, stream>>>(zv1, stV1, dgG, dgC);
        dg35_fin<<<1, 256, 0, stream>>>(stV1, vg1 + (l-1)*dgC, vbb1 + (l-1)*dgC,
                                        abv1, 1.f/dgG, dgC, 1);
        dg35_gemm_v<<<dim3(16,2), 256, 0, stream>>>(zv1, vW2 + (l-1)*dgC*dgC,
                                                    vb2 + (l-1)*dgC, abv1,
                                                    zv2, dgG, dgC, dgC, 1);
        dg35_cs4<<<64, 256, 0, stream>>>(zv2, stV2, dgG, dgC);
        dg35_fin<<<1, 256, 0, stream>>>(stV2, vg2 + (l-1)*dgC, vbb2 + (l-1)*dgC,
                                        abv2, 1.f/dgG, dgC, 1);
        dg35_vnfin<<<(dgG*dgC)/256, 256, 0, stream>>>(zv2, abv2, vn);
        dg35_addvn<<<dgN, dgC, 0, stream>>>(h2, vn, batch, af);
        hin = h2;
      }
      dg35_gb<<<dgN, dgC, 0, stream>>>(hin, packed, off, bemb, hh, af);
      dg35_gemm_h<<<dim3(gx,4), 256, 0, stream>>>(hh, cW1 + l*dgC*dgC2,
                                                  cb1 + l*dgC2, (const float*)0,
                                                  (const void*)0, z,
                                                  dgN, dgC, dgC2, 0, 0, af);
      dg35_colstats<<<128, 256, 0, stream>>>(z, st1, dgN, dgC2, af);
      dg35_fin<<<1, 256, 0, stream>>>(st1, cg1 + l*dgC2, cbb1 + l*dgC2,
                                      ab1, 1.f/dgN, dgC2, 1);
      dg35_gemm_h<<<dim3(gx,2), 256, 0, stream>>>(z, cW2 + l*dgC2*dgC,
                                                  cb2 + l*dgC, ab1, h, h,
                                                  dgN, dgC2, dgC, 1, (l==0)?0:1, af);
    }
    hipMemsetAsync(stH, 0, sizeof(float)*2*dgC, stream);
    dg35_colstats<<<128, 256, 0, stream>>>(h, stH, dgN, dgC, af);
    dg35_fin<<<1, 256, 0, stream>>>(stH, ng + 6*dgC, nb + 6*dgC, abh, 1.f/dgN, dgC, 1);
    dg35_out<<<dgG, dgC, 0, stream>>>(h, abh, gs, out, af);
  }
}